// Round 14
// baseline (574.223 us; speedup 1.0000x reference)
//
#include <hip/hip_runtime.h>
#include <cstdint>

// SlimmableMoE: B=4,S=1024,D=1024,E=8,F=4096,W=768,H=6,HD=128,TOPK=2
#define NE 8
#define NB 4
#define NS 1024
#define ND 1024
#define NF 4096
#define NW 768
#define NH 6
#define NHD 128
#define NTOK 4096   // B*S
#define NBH 24      // B*H
#define RCAP 10496  // compacted-row capacity (max Rtotal=10240 + tile over-read)
#define VSTRIDE ((size_t)NTOK * NW)   // per-expert V^T extent = B*H*HD*S = 3145728
#define EPS 1e-6f

typedef unsigned short ush;
typedef __attribute__((ext_vector_type(8))) short short8;   // 8 bf16 = 4 VGPR
typedef __attribute__((ext_vector_type(4))) float f32x4;
typedef __attribute__((ext_vector_type(4))) unsigned short u16x4;

typedef const __attribute__((address_space(1))) void gvoid_t;
typedef __attribute__((address_space(3))) void lvoid_t;

__device__ __forceinline__ void gload16(const void* g, void* l) {
  __builtin_amdgcn_global_load_lds((gvoid_t*)g, (lvoid_t*)l, 16, 0, 0);
}

__device__ __forceinline__ ush f2b(float f) {
  union { float f; uint32_t u; } x; x.f = f;
  uint32_t r = x.u + 0x7fffu + ((x.u >> 16) & 1u);
  return (ush)(r >> 16);
}
__device__ __forceinline__ float b2f(ush u) {
  union { uint32_t u; float f; } x; x.u = (uint32_t)u << 16;
  return x.f;
}
__device__ __forceinline__ int prefix_sum(const int* __restrict__ c, int n) {
  int s = 0;
#pragma unroll 1
  for (int i = 0; i < n; ++i) s += c[i];
  return s;
}

// ---- pipelined-GEMM LDS packing (validated R9/R10) ----
// vrow u (128 B) holds logical rows u (bytes 0-63) and u+PAIR (bytes 64-127),
// bytes swizzled ^((u&7)<<4). Staging: chunk c, dst = base + c*4096 + tid*16 (linear);
// source row/kbyte from the inverse swizzle.

// ---------------- router: logits->softmax->top2->gate; init inv map ----------------
__global__ __launch_bounds__(256, 4)
void router_kernel(const float* __restrict__ x, const float* __restrict__ wr,
                   float* __restrict__ gate, int* __restrict__ inv) {
  int lane = threadIdx.x & 63, wave = threadIdx.x >> 6;
  int t = blockIdx.x * 4 + wave;
  float acc[NE] = {};
  for (int i = 0; i < 16; ++i) {
    int d = lane + i * 64;
    float xv = x[(size_t)t * ND + d];
    const float* wp = wr + (size_t)d * NE;
    float4 w0 = *(const float4*)wp, w1 = *(const float4*)(wp + 4);
    acc[0] += xv * w0.x; acc[1] += xv * w0.y; acc[2] += xv * w0.z; acc[3] += xv * w0.w;
    acc[4] += xv * w1.x; acc[5] += xv * w1.y; acc[6] += xv * w1.z; acc[7] += xv * w1.w;
  }
#pragma unroll
  for (int e = 0; e < NE; ++e)
    for (int m = 1; m < 64; m <<= 1) acc[e] += __shfl_xor(acc[e], m);
  int i1 = 0; float v1 = acc[0];
#pragma unroll
  for (int e = 1; e < NE; ++e) if (acc[e] > v1) { v1 = acc[e]; i1 = e; }
  int i2 = -1; float v2 = -3.0e38f;
#pragma unroll
  for (int e = 0; e < NE; ++e) if (e != i1 && acc[e] > v2) { v2 = acc[e]; i2 = e; }
  float p2 = __expf(v2 - v1);          // p1 = 1
  float g1 = 1.0f / (1.0f + p2), g2 = p2 / (1.0f + p2);
  if (lane < NE)
    gate[(size_t)t * NE + lane] = (lane == i1) ? g1 : ((lane == i2) ? g2 : 0.0f);
  if (lane < 2) inv[t * 2 + lane] = -1;
}

// ---------------- per-expert routed-token index lists + inverse map ----------------
__global__ __launch_bounds__(1024, 1)
void build_index(const float* __restrict__ gate, int* __restrict__ cnt64s,
                 int* __restrict__ idx_all, int* __restrict__ inv) {
  int e = blockIdx.x >> 2, b = blockIdx.x & 3;
  int s = threadIdx.x, t = b * 1024 + s;
  bool on = gate[(size_t)t * NE + e] > 0.0f;
  idx_all[(e * 4 + b) * 1024 + s] = (b * 1024) | (int)0x80000000;   // pad default
  __shared__ int wsum[16], wbase[16];
  unsigned long long mask = __ballot(on);
  int lane = s & 63, wv = s >> 6;
  if (lane == 0) wsum[wv] = __popcll(mask);
  __syncthreads();
  if (s == 0) {
    int acc = 0;
    for (int i = 0; i < 16; ++i) { wbase[i] = acc; acc += wsum[i]; }
    cnt64s[e * 4 + b] = (acc + 63) & ~63;
  }
  __syncthreads();
  if (on) {
    int pos = wbase[wv] + __popcll(mask & ((1ull << lane) - 1ull));
    idx_all[(e * 4 + b) * 1024 + pos] = t;
    int k = 0;
#pragma unroll
    for (int j = 0; j < NE; ++j) k += (j < e && gate[(size_t)t * NE + j] > 0.0f);
    inv[t * 2 + k] = (e << 12) | pos;
  }
}

// ---------------- all casts f32->bf16 in one launch: y=0..7 expert weights, y=8 xs ----------------
__global__ __launch_bounds__(256, 4)
void cast_all(const float* __restrict__ x,
              const float* __restrict__ qw, const float* __restrict__ kw,
              const float* __restrict__ vw, const float* __restrict__ ow,
              const float* __restrict__ w1, const float* __restrict__ w2,
              ush* __restrict__ xs,
              ush* __restrict__ dq, ush* __restrict__ dk, ush* __restrict__ dv,
              ush* __restrict__ dwo, ush* __restrict__ d1, ush* __restrict__ d2) {
  int y = blockIdx.y;
  if (y == 8) {
    const int n4 = NTOK * NW / 4;
    for (int u = blockIdx.x * 256 + threadIdx.x; u < n4; u += gridDim.x * 256) {
      int r = u / (NW / 4), c = u - r * (NW / 4);
      float4 v = *(const float4*)(x + (size_t)r * ND + c * 4);
      u16x4 o; o.x = f2b(v.x); o.y = f2b(v.y); o.z = f2b(v.z); o.w = f2b(v.w);
      *(u16x4*)(xs + (size_t)u * 4) = o;
    }
    return;
  }
  const int e = y;
  const int Q4 = 147456;   // 768*768/4
  const int W14 = 786432;  // 4096*768/4
  const int total = 4 * Q4 + 2 * W14;
  const float* qe = qw + (size_t)e * ND * ND;
  const float* ke = kw + (size_t)e * ND * ND;
  const float* ve = vw + (size_t)e * ND * ND;
  const float* oe = ow + (size_t)e * ND * ND;
  const float* w1e = w1 + (size_t)e * NF * ND;
  const float* w2e = w2 + (size_t)e * ND * NF;
  ush* dqe = dq + (size_t)e * NW * NW;
  ush* dke = dk + (size_t)e * NW * NW;
  ush* dve = dv + (size_t)e * NW * NW;
  ush* doe = dwo + (size_t)e * NW * NW;
  ush* d1e = d1 + (size_t)e * NF * NW;
  ush* d2e = d2 + (size_t)e * NW * NF;
  for (int u = blockIdx.x * 256 + threadIdx.x; u < total; u += gridDim.x * 256) {
    const float* src; ush* dst; int ldsrc, cols4, rel;
    if (u < 4 * Q4) {
      int which = u / Q4; rel = u - which * Q4;
      src = (which == 0) ? qe : (which == 1) ? ke : (which == 2) ? ve : oe;
      dst = (which == 0) ? dqe : (which == 1) ? dke : (which == 2) ? dve : doe;
      ldsrc = 1024; cols4 = 192;
    } else if (u < 4 * Q4 + W14) {
      rel = u - 4 * Q4; src = w1e; dst = d1e; ldsrc = 1024; cols4 = 192;
    } else {
      rel = u - 4 * Q4 - W14; src = w2e; dst = d2e; ldsrc = 4096; cols4 = 1024;
    }
    int r = rel / cols4, c = rel - r * cols4;
    float4 v = *(const float4*)(src + (size_t)r * ldsrc + (size_t)c * 4);
    u16x4 o; o.x = f2b(v.x); o.y = f2b(v.y); o.z = f2b(v.z); o.w = f2b(v.w);
    *(u16x4*)(dst + (size_t)rel * 4) = o;
  }
}

#define BM 128
#define BN 128

// fast tanh-form gelu (~12 VALU vs ~30 for erff); |err| vs exact <~1e-3
__device__ __forceinline__ float gelu_fast(float v) {
  float u = v * fmaf(0.0356774081f, v * v, 0.7978845608f);
  float p = __expf(2.0f * fabsf(u));               // e^{2|u|} (inf-safe)
  float th = fmaf(-2.0f, __builtin_amdgcn_rcpf(p + 1.0f), 1.0f);
  th = copysignf(th, u);
  return 0.5f * v * (1.0f + th);
}

// staging-geometry (validated R9/R10): vrow u, pair offset PAIR
__device__ __forceinline__ void stage_geom2(int tid, int u, int PAIR, int& row, int& kb) {
  row = u + PAIR * (((tid >> 2) ^ (u >> 2)) & 1);
  kb = ((tid ^ u) & 3) << 4;
}

// ---------------- batched QKV GEMM (narrow 128x128, 3-slot BK=32 pipeline) ----------------
// 1-D grid nwg = 8*576; e = bid&7 (XCD-pinned), wi = bid>>3: bn=wi%6, bm=(wi/6)%32, w=wi/192
// V^T output transposed through LDS (reused pipeline slots) for coalesced writes.
__global__ __launch_bounds__(256, 3)
void qkv_gemm(const ush* __restrict__ A,
              const ush* __restrict__ wqb, const ush* __restrict__ wkb,
              const ush* __restrict__ wvb,
              const float* __restrict__ qbias, const float* __restrict__ kbias,
              const float* __restrict__ vbias,
              ush* __restrict__ qg, ush* __restrict__ kg, ush* __restrict__ vtg,
              const int* __restrict__ cnt64s, const int* __restrict__ idx_all) {
  const int bid = blockIdx.x;
  const int e = bid & 7, wi = bid >> 3;
  const int bn = wi % 6, bm = (wi / 6) % 32, w = wi / 192;
  int sb = 0, cnt = 0;
  if (w == 0) {
    int sec = e * 4 + (bm >> 3);
    cnt = cnt64s[sec];
    if (((bm & 7) * 128) >= cnt) return;
    sb = prefix_sum(cnt64s, sec);
  }
  const ush* Bw = ((w == 0) ? wqb : (w == 1) ? wkb : wvb) + (size_t)e * NW * NW;
  const float* bias = ((w == 0) ? qbias : (w == 1) ? kbias : vbias) + (size_t)e * ND;

  __shared__ __align__(16) char LDS[3 * 16384];

  const int tid = threadIdx.x, lane = tid & 63, wave = tid >> 6;
  const int lr = lane & 15, lg = lane >> 4;
  const int wr = wave >> 1, wc = wave & 1;

  size_t srcOff[4];
#pragma unroll
  for (int c = 0; c < 4; ++c) {
    int u = (c & 1) * 32 + (tid >> 3), row, kb;
    stage_geom2(tid, u, 64, row, kb);
    int gRow;
    if (c < 2) {
      if (w == 0) {
        int lrow = (bm & 7) * 128 + row;
        gRow = idx_all[(e * 4 + (bm >> 3)) * 1024 + lrow] & 0x7fffffff;
      } else {
        gRow = bm * BM + row;
      }
    } else {
      gRow = bn * BN + row;
    }
    srcOff[c] = (size_t)gRow * (NW * 2) + kb;
  }

  int offA[4], offB[4];
#pragma unroll
  for (int i = 0; i < 4; ++i) {
    offA[i] = (i * 16 + lr) * 128 + (((wr << 6) | (lg << 4)) ^ ((lr & 7) << 4));
    offB[i] = (i * 16 + lr) * 128 + (((wc << 6) | (lg << 4)) ^ ((lr & 7) << 4)) + 8192;
  }

  auto stg = [&](int slot, int kt) {
    size_t kOff = (size_t)kt * 64;
    char* dst = LDS + slot * 16384;
#pragma unroll
    for (int c = 0; c < 4; ++c) {
      const char* src = (c < 2) ? (const char*)A + srcOff[c] + kOff
                                : (const char*)Bw + srcOff[c] + kOff;
      gload16(src, dst + c * 4096 + tid * 16);
    }
  };

  f32x4 acc[4][4] = {};
  const int nkt = NW / 32;   // 24
  stg(0, 0); stg(1, 1);
  asm volatile("s_waitcnt vmcnt(4)" ::: "memory");
  asm volatile("s_barrier" ::: "memory");
  int slot = 0;
  for (int kt = 0; kt < nkt; ++kt) {
    int s2 = slot + 2; if (s2 >= 3) s2 -= 3;
    bool more = (kt + 2 < nkt);
    if (more) stg(s2, kt + 2);
    const char* base = LDS + slot * 16384;
    short8 af[4], bfr[4];
#pragma unroll
    for (int i = 0; i < 4; ++i) {
      af[i] = *(const short8*)(base + offA[i]);
      bfr[i] = *(const short8*)(base + offB[i]);
    }
    __builtin_amdgcn_s_setprio(1);
#pragma unroll
    for (int i = 0; i < 4; ++i)
#pragma unroll
      for (int j = 0; j < 4; ++j)
        acc[i][j] = __builtin_amdgcn_mfma_f32_16x16x32_bf16(af[i], bfr[j], acc[i][j], 0, 0, 0);
    __builtin_amdgcn_s_setprio(0);
    if (more) asm volatile("s_waitcnt vmcnt(4)" ::: "memory");
    else      asm volatile("s_waitcnt vmcnt(0)" ::: "memory");
    asm volatile("s_barrier" ::: "memory");
    slot = (slot == 2) ? 0 : slot + 1;
  }

  if (w == 2) {
    // V^T: transpose through LDS (pipeline slots dead after final barrier).
    // Tile T[d][s]: d=0..127 rows of 256B, byte addr = d*256 + ((s*2) ^ ((d&15)<<4)).
#pragma unroll
    for (int i = 0; i < 4; ++i) {
      int sl = wr * 64 + i * 16 + lg * 4;          // section-local s
#pragma unroll
      for (int j = 0; j < 4; ++j) {
        int d = wc * 64 + j * 16 + lr;
        float bb = bias[bn * BN + d];
        u16x4 wv_;
#pragma unroll
        for (int r = 0; r < 4; ++r) wv_[r] = f2b(acc[i][j][r] + bb);
        *(u16x4*)(LDS + d * 256 + ((sl * 2) ^ ((d & 15) << 4))) = wv_;
      }
    }
    __syncthreads();
    // stream out: thread -> (d = tid>>1, s-half = (tid&1)*64); 8 x 16B coalesced stores
    int d = tid >> 1, sh = (tid & 1) * 64;
    int b_ = bm >> 3, s0b = (bm & 7) * 128;
    ush* gdst = vtg + (size_t)e * VSTRIDE +
                ((size_t)(b_ * NH + bn) * NHD + d) * NS + s0b + sh;
#pragma unroll
    for (int c = 0; c < 8; ++c) {
      short8 v = *(const short8*)(LDS + d * 256 + (((sh + c * 8) * 2) ^ ((d & 15) << 4)));
      *(short8*)(gdst + c * 8) = v;
    }
    return;
  }

#pragma unroll
  for (int i = 0; i < 4; ++i) {
    int lm16 = (bm & 7) * 128 + wr * 64 + i * 16;            // Q: section-local 16-row group
    int m0 = bm * BM + wr * 64 + i * 16 + lg * 4;            // dense row
#pragma unroll
    for (int j = 0; j < 4; ++j) {
      int n = bn * BN + wc * 64 + j * 16 + lr;
      float bb = bias[n];
      if (w == 0) {
        if (lm16 < cnt) {
          int grow = sb + lm16 + lg * 4;
#pragma unroll
          for (int r = 0; r < 4; ++r)
            qg[(size_t)(grow + r) * NW + n] = f2b(acc[i][j][r] + bb);
        }
      } else {
        ush* o = kg + (size_t)e * NTOK * NW;
#pragma unroll
        for (int r = 0; r < 4; ++r)
          o[(size_t)(m0 + r) * NW + n] = f2b(acc[i][j][r] + bb);
      }
    }
  }
}

// ---------------- batched flash attention: 2-slot counted-vmcnt K/V pipeline ----------------
// 1-D grid 8*384; e = bid&7; wi = bid>>3: qb = wi&15, bh = wi>>4 in [0,24)
// Per kt: stage(next slot) issued BEFORE compute; drain covered by QK+softmax+PV (~700cyc).
__global__ __launch_bounds__(256, 2)
void attn2(const ush* __restrict__ Qg, const ush* __restrict__ Kg,
           const ush* __restrict__ VTg, ush* __restrict__ ao,
           const int* __restrict__ cnt64s) {
  const int bid = blockIdx.x;
  const int e = bid & 7, wi = bid >> 3;
  const int qb = wi & 15, bh = wi >> 4;
  const int b = bh / NH, h = bh % NH;
  const int sec = e * 4 + b;
  const int cnt = cnt64s[sec];
  if (qb * 64 >= cnt) return;
  const int sb = prefix_sum(cnt64s, sec);

  __shared__ __align__(16) char KV[2][32768];   // per slot: K 16KB (64x128) + V^T 16KB (128x64)
  __shared__ __align__(16) ush Ps[4 * 16 * 64];

  const int tid = threadIdx.x, lane = tid & 63, wave = tid >> 6;
  const int lr = lane & 15, lg = lane >> 4;
  const float cexp = 1.4426950408889634f / sqrtf((float)NHD);

  const ush* Ke = Kg + (size_t)e * NTOK * NW;
  const ush* Ve = VTg + (size_t)e * VSTRIDE;

  int growq = sb + qb * 64 + wave * 16 + lr;
  short8 qf[4];
#pragma unroll
  for (int kk = 0; kk < 4; ++kk)
    qf[kk] = *(const short8*)(Qg + (size_t)growq * NW + h * NHD + kk * 32 + lg * 8);

  // per-thread staging source offsets (precomputed, kt-invariant part)
  int kRow[4], kCb[4], vD[4], vCb[4];
#pragma unroll
  for (int p = 0; p < 4; ++p) {
    int o = p * 4096 + tid * 16;
    kRow[p] = o >> 8; kCb[p] = (o & 255) ^ ((kRow[p] & 7) << 4);
    vD[p] = o >> 7;   vCb[p] = (o & 127) ^ ((vD[p] & 7) << 4);
  }

  auto stg = [&](int slot, int kt) {
    char* dst = &KV[slot][0];
#pragma unroll
    for (int p = 0; p < 4; ++p)
      gload16((const char*)Ke + ((size_t)(b * NS + kt * 64 + kRow[p]) * NW + h * NHD) * 2 + kCb[p],
              dst + p * 4096 + tid * 16);
#pragma unroll
    for (int p = 0; p < 4; ++p)
      gload16((const char*)Ve + ((size_t)((b * NH + h) * NHD + vD[p]) * NS + kt * 64) * 2 + vCb[p],
              dst + 16384 + p * 4096 + tid * 16);
  };

  f32x4 accv[8] = {};
  float mr[4] = {-3.0e38f, -3.0e38f, -3.0e38f, -3.0e38f};
  float ls[4] = {};

  stg(0, 0);
  asm volatile("s_waitcnt vmcnt(0)" ::: "memory");
  asm volatile("s_barrier" ::: "memory");

  for (int kt = 0; kt < 16; ++kt) {   // 16 x 64 keys = all 1024
    const int cur = kt & 1;
    const bool more = (kt + 1 < 16);
    if (more) stg(cur ^ 1, kt + 1);    // issue next tile; drain after compute
    const char* Ks = &KV[cur][0];
    const char* VTs = &KV[cur][16384];

    f32x4 s[4] = {};
    __builtin_amdgcn_s_setprio(1);
#pragma unroll
    for (int kg2 = 0; kg2 < 4; ++kg2)
#pragma unroll
      for (int kk = 0; kk < 4; ++kk) {
        int row = kg2 * 16 + lr;
        short8 kf = *(const short8*)(Ks + row * 256 +
                                     ((kk * 64 + lg * 16) ^ ((row & 7) << 4)));
        s[kg2] = __builtin_amdgcn_mfma_f32_16x16x32_bf16(qf[kk], kf, s[kg2], 0, 0, 0);
      }
    __builtin_amdgcn_s_setprio(0);

    float mt[4];
#pragma unroll
    for (int r = 0; r < 4; ++r) {
      float m0 = fmaxf(fmaxf(s[0][r], s[1][r]), fmaxf(s[2][r], s[3][r]));
#pragma unroll
      for (int mm = 1; mm < 16; mm <<= 1) m0 = fmaxf(m0, __shfl_xor(m0, mm));
      mt[r] = m0;
    }
    bool need = (mt[0] > mr[0] + 8.f) || (mt[1] > mr[1] + 8.f) ||
                (mt[2] > mr[2] + 8.f) || (mt[3] > mr[3] + 8.f);
    if (__any(need)) {
#pragma unroll
      for (int r = 0; r < 4; ++r) {
        float mn = fmaxf(mr[r], mt[r]);
        float sc = exp2f((mr[r] - mn) * cexp);
        mr[r] = mn; ls[r] *= sc;
#pragma unroll
        for (int dg = 0; dg < 8; ++dg) accv[dg][r] *= sc;
      }
    }

    char* pw = (char*)Ps + wave * 2048;
#pragma unroll
    for (int kg2 = 0; kg2 < 4; ++kg2)
#pragma unroll
      for (int r = 0; r < 4; ++r) {
        float p = exp2f((s[kg2][r] - mr[r]) * cexp);
        ls[r] += p;
        int row = lg * 4 + r;
        *(ush*)(pw + row * 128 + (((kg2 * 16 + lr) * 2) ^ ((row & 7) << 4))) = f2b(p);
      }
    short8 pf[2];
#pragma unroll
    for (int kk2 = 0; kk2 < 2; ++kk2)
      pf[kk2] = *(const short8*)(pw + lr * 128 + ((kk2 * 64 + lg * 16) ^ ((lr & 7) << 4)));

    __builtin_amdgcn_s_setprio(1);
#pragma unroll
    for (int dg = 0; dg < 8; ++dg) {
      int d = dg * 16 + lr;
#pragma unroll
      for (int kk2 = 0; kk2 < 2; ++kk2) {
        short8 vf = *(const short8*)(VTs + d * 128 +
                                     ((kk2 * 64 + lg * 16) ^ ((d & 7) << 4)));
        accv[dg] = __builtin_amdgcn_mfma_f32_16x16x32_bf16(pf[kk2], vf, accv[dg], 0, 0, 0);
      }
    }
    __builtin_amdgcn_s_setprio(0);

    if (more) asm volatile("s_waitcnt vmcnt(0)" ::: "memory");  // next tile landed
    asm volatile("s_barrier" ::: "memory");   // all waves done with cur; next visible
  }

  // reduce l across row group, normalize, write AO directly
#pragma unroll
  for (int r = 0; r < 4; ++r)
#pragma unroll
    for (int mm = 1; mm < 16; mm <<= 1) ls[r] += __shfl_xor(ls[r], mm);

#pragma unroll
  for (int r = 0; r < 4; ++r) {
    int growr = sb + qb * 64 + wave * 16 + lg * 4 + r;
    float inv_ = 1.0f / ls[r];
#pragma unroll
    for (int dg = 0; dg < 8; ++dg)
      ao[(size_t)growr * NW + h * NHD + dg * 16 + lr] = f2b(accv[dg][r] * inv_);
  }
}

// ---------------- CSR GEMM wide: 128x256 tile, 4x8 acc, 3-slot BK=32 pipeline (FFN1) ----------------
__global__ __launch_bounds__(256, 2)
void csr_gemm_w(const ush* __restrict__ A, const ush* __restrict__ Ball,
                const float* __restrict__ biasAll, ush* __restrict__ out,
                int N, int Kld, int klen, int nbn,
                int strideBe, int biasStride,
                const int* __restrict__ cnt64s) {
  const int bid = blockIdx.x;
  const int e = bid & 7, wi = bid >> 3;
  const int bn = wi % nbn, bm = wi / nbn;
  const int Re = cnt64s[e * 4] + cnt64s[e * 4 + 1] + cnt64s[e * 4 + 2] + cnt64s[e * 4 + 3];
  if (bm * BM >= Re) return;
  const int ebase = prefix_sum(cnt64s, e * 4);
  const ush* Bw = Ball + (size_t)e * strideBe;
  const float* bias = biasAll + (size_t)e * biasStride;

  __shared__ __align__(16) char LDS[3 * 24576];

  const int tid = threadIdx.x, lane = tid & 63, wave = tid >> 6;
  const int lr = lane & 15, lg = lane >> 4;
  const int wr = wave >> 1, wc = wave & 1;

  size_t srcOff[6];
#pragma unroll
  for (int c = 0; c < 2; ++c) {
    int u = c * 32 + (tid >> 3), row, kb;
    stage_geom2(tid, u, 64, row, kb);
    srcOff[c] = (size_t)(ebase + bm * BM + row) * (Kld * 2) + kb;
  }
#pragma unroll
  for (int c = 0; c < 4; ++c) {
    int u = c * 32 + (tid >> 3), row, kb;
    stage_geom2(tid, u, 128, row, kb);
    srcOff[2 + c] = (size_t)(bn * 256 + row) * (Kld * 2) + kb;
  }

  int offA[4], offB[8];
#pragma unroll
  for (int i = 0; i < 4; ++i)
    offA[i] = (i * 16 + lr) * 128 + (((wr << 6) | (lg << 4)) ^ ((lr & 7) << 4));
#pragma unroll
  for (int j = 0; j < 8; ++j)
    offB[j] = (j * 16 + lr) * 128 + (((wc << 6) | (lg << 4)) ^ ((lr & 7) << 4)) + 8192;

  auto stg = [&](int slot, int kt) {
    size_t kOff = (size_t)kt * 64;
    char* dst = LDS + slot * 24576;
#pragma unroll
    for (int c = 0; c < 2; ++c)
      gload16((const char*)A + srcOff[c] + kOff, dst + c * 4096 + tid * 16);
#pragma unroll
    for (int c = 0; c < 4; ++c)
      gload16((const char*)Bw + srcOff[2 + c] + kOff, dst + 8192 + c * 4096 + tid * 16);
  };

  f32x4 acc[4][8] = {};
  const int nkt = klen / 32;
  stg(0, 0); stg(1, 1);
  asm volatile("s_waitcnt vmcnt(6)" ::: "memory");
  asm volatile("s_barrier" ::: "memory");
  int slot = 0;
  for (int kt = 0; kt < nkt; ++kt) {
    int s2 = slot + 2; if (s2 >= 3) s2 -= 3;
    bool more = (kt + 2 < nkt);
    if (more) stg(s2, kt + 2);
    const char* base = LDS + slot * 24576;
    short8 af[4], bfr[8];
#pragma unroll
    for (int i = 0; i < 4; ++i) af[i] = *(const short8*)(base + offA[i]);
#pragma unroll
    for (int j = 0; j < 8; ++j) bfr[j] = *(const short8*)(base + offB[j]);
    __builtin_amdgcn_s_setprio(1);
#pragma unroll
    for (int i = 0; i < 4; ++i)
#pragma unroll
      for (int j = 0; j < 8; ++j)
        acc[i][j] = __builtin_amdgcn_mfma_f32_16x16x32_bf16(af[i], bfr[j], acc[i][j], 0, 0, 0);
    __builtin_amdgcn_s_setprio(0);
    if (more) asm volatile("s_waitcnt vmcnt(6)" ::: "memory");
    else      asm volatile("s_waitcnt vmcnt(0)" ::: "memory");
    asm volatile("s_barrier" ::: "memory");
    slot = (slot == 2) ? 0 : slot + 1;
  }

#pragma unroll
  for (int i = 0; i < 4; ++i) {
    int lm16 = bm * BM + wr * 64 + i * 16;
    if (lm16 >= Re) continue;
#pragma unroll
    for (int j = 0; j < 8; ++j) {
      int n = bn * 256 + wc * 128 + j * 16 + lr;
      float bb = bias[n];
      int row0 = ebase + lm16 + lg * 4;
#pragma unroll
      for (int r = 0; r < 4; ++r)
        out[(size_t)(row0 + r) * N + n] = f2b(gelu_fast(acc[i][j][r] + bb));
    }
  }
}

// ---------------- CSR GEMM (128x128, 3-slot BK=32 pipeline; o-proj & FFN2) ----------------
__global__ __launch_bounds__(256, 3)
void csr_gemm(const ush* __restrict__ A, const ush* __restrict__ Ball,
              const float* __restrict__ biasAll, ush* __restrict__ out,
              int N, int Kld, int klen, int nbn, int nbm, int nsplit,
              int strideBe, int biasStride,
              const int* __restrict__ cnt64s) {
  const int bid = blockIdx.x;
  const int e = bid & 7, wi = bid >> 3;
  const int bn = wi % nbn, bm = (wi / nbn) % nbm, s = wi / (nbn * nbm);
  const int Re = cnt64s[e * 4] + cnt64s[e * 4 + 1] + cnt64s[e * 4 + 2] + cnt64s[e * 4 + 3];
  if (bm * BM >= Re) return;
  const int ebase = prefix_sum(cnt64s, e * 4);
  const ush* Bw = Ball + (size_t)e * strideBe;
  const float* bias = (s == 0) ? biasAll + (size_t)e * biasStride : nullptr;
  const int koff = s * klen;
  ush* outp = out + (size_t)s * RCAP * N;

  __shared__ __align__(16) char LDS[3 * 16384];

  const int tid = threadIdx.x, lane = tid & 63, wave = tid >> 6;
  const int lr = lane & 15, lg = lane >> 4;
  const int wr = wave >> 1, wc = wave & 1;

  size_t srcOff[4];
#pragma unroll
  for (int c = 0; c < 4; ++c) {
    int u = (c & 1) * 32 + (tid >> 3), row, kb;
    stage_geom2(tid, u, 64, row, kb);
    int gRow = (c < 2) ? (ebase + bm * BM + row) : (bn * BN + row);
    srcOff[c] = (size_t)gRow * (Kld * 2) + (size_t)koff * 2 + kb;
  }

  int offA[4], offB[4];
#pragma unroll
  for (int i = 0; i < 4; ++i) {
    offA[i] = (i * 16 + lr) * 128 + (((wr << 6) | (lg << 4)) ^ ((lr & 7) << 4));
    offB[i] = (i * 16 + lr) * 128 + (((wc << 6) | (lg << 4)) ^ ((lr & 7) << 4)) + 8192;
  }

  auto stg = [&](int slot, int kt) {
    size_t kOff = (size_t)kt * 64;
    char* dst = LDS + slot * 16384;
#pragma unroll
    for (int c = 0; c < 4; ++c) {
      const char* src = (c < 2) ? (const char*)A + srcOff[c] + kOff
                                : (const char*)Bw + srcOff[c] + kOff;
      gload16(src, dst + c * 4096 + tid * 16);
    }
  };

  f32x4 acc[4][4] = {};
  const int nkt = klen / 32;
  stg(0, 0); stg(1, 1);
  asm volatile("s_waitcnt vmcnt(4)" ::: "memory");
  asm volatile("s_barrier" ::: "memory");
  int slot = 0;
  for (int kt = 0; kt < nkt; ++kt) {
    int s2 = slot + 2; if (s2 >= 3) s2 -= 3;
    bool more = (kt + 2 < nkt);
    if (more) stg(s2, kt + 2);
    const char* base = LDS + slot * 16384;
    short8 af[4], bfr[4];
#pragma unroll
    for (int i = 0; i < 4; ++i) {
      af[i] = *(const short8*)(base + offA[i]);
      bfr[i] = *(const short8*)(base + offB[i]);
    }
    __builtin_amdgcn_s_setprio(1);
#pragma unroll
    for (int i = 0; i < 4; ++i)
#pragma unroll
      for (int j = 0; j < 4; ++j)
        acc[i][j] = __builtin_amdgcn_mfma_f32_16x16x32_bf16(af[i], bfr[j], acc[i][j], 0, 0, 0);
    __builtin_amdgcn_s_setprio(0);
    if (more) asm volatile("s_waitcnt vmcnt(4)" ::: "memory");
    else      asm volatile("s_waitcnt vmcnt(0)" ::: "memory");
    asm volatile("s_barrier" ::: "memory");
    slot = (slot == 2) ? 0 : slot + 1;
  }

#pragma unroll
  for (int i = 0; i < 4; ++i) {
    int lm16 = bm * BM + wr * 64 + i * 16;
    if (lm16 >= Re) continue;                  // cross-expert guard (Re % 64 == 0)
#pragma unroll
    for (int j = 0; j < 4; ++j) {
      int n = bn * BN + wc * 64 + j * 16 + lr;
      float bb = bias ? bias[n] : 0.0f;
      int row0 = ebase + lm16 + lg * 4;
#pragma unroll
      for (int r = 0; r < 4; ++r)
        outp[(size_t)(row0 + r) * N + n] = f2b(acc[i][j][r] + bb);
    }
  }
}

// ---------------- residual + RMSNorm over compacted rows (single o-proj partial) ----------------
__global__ __launch_bounds__(256, 4)
void rmsnorm_res(const float* __restrict__ x, const ush* __restrict__ ooP,
                 ush* __restrict__ x1b, const int* __restrict__ cnt64s,
                 const int* __restrict__ idx_all) {
  int r = blockIdx.x;
  int base = 0, sec = -1, loc = 0;
#pragma unroll 1
  for (int i = 0; i < 32; ++i) {
    int cc = cnt64s[i];
    if (sec < 0 && r < base + cc) { sec = i; loc = r - base; }
    base += cc;
  }
  if (sec < 0) return;
  int t = idx_all[sec * 1024 + loc] & 0x7fffffff;
  __shared__ float red[4];
  int c = threadIdx.x, lane = c & 63, wave = c >> 6;
  float v[3]; float ss = 0.0f;
#pragma unroll
  for (int i = 0; i < 3; ++i) {
    int col = c + i * 256;
    float a = x[(size_t)t * ND + col] + b2f(ooP[(size_t)r * NW + col]);
    v[i] = a; ss += a * a;
  }
#pragma unroll
  for (int m = 1; m < 64; m <<= 1) ss += __shfl_xor(ss, m);
  if (lane == 0) red[wave] = ss;
  __syncthreads();
  float tot = red[0] + red[1] + red[2] + red[3];
  float scale = rsqrtf(tot / (float)NW + EPS);
#pragma unroll
  for (int i = 0; i < 3; ++i) {
    int col = c + i * 256;
    x1b[(size_t)r * NW + col] = f2b(v[i] * scale);
  }
}

// ---------------- final: per token, gather both experts, rmsnorm, gate-sum (2 ffp partials) ----------------
__global__ __launch_bounds__(256, 4)
void final_token(const ush* __restrict__ x1b, const ush* __restrict__ ffp,
                 const float* __restrict__ gate, const int* __restrict__ inv,
                 const int* __restrict__ cnt64s, float* __restrict__ out) {
  int t = blockIdx.x, c = threadIdx.x, lane = c & 63, wave = c >> 6;
  __shared__ float red[4];
  float acc[3] = {0.0f, 0.0f, 0.0f};
#pragma unroll 1
  for (int k = 0; k < 2; ++k) {
    int v = inv[t * 2 + k];
    if (v >= 0) {
      int e = v >> 12, pos = v & 0xfff;
      int b = t >> 10;
      int grow = prefix_sum(cnt64s, e * 4 + b) + pos;
      float g = gate[(size_t)t * NE + e];
      float vv[3]; float ss = 0.0f;
#pragma unroll
      for (int i = 0; i < 3; ++i) {
        int col = c + i * 256;
        float f = b2f(ffp[(size_t)grow * NW + col]) +
                  b2f(ffp[(size_t)RCAP * NW + (size_t)grow * NW + col]);
        float a = b2f(x1b[(size_t)grow * NW + col]) + f;
        vv[i] = a; ss += a * a;
      }
#pragma unroll
      for (int m = 1; m < 64; m <<= 1) ss += __shfl_xor(ss, m);
      if (lane == 0) red[wave] = ss;
      __syncthreads();
      float tot = red[0] + red[1] + red[2] + red[3];
      float scale = rsqrtf(tot / (float)NW + EPS) * g;
#pragma unroll
      for (int i = 0; i < 3; ++i) acc[i] += vv[i] * scale;
      __syncthreads();
    }
  }
#pragma unroll
  for (int i = 0; i < 3; ++i) out[(size_t)t * ND + c + i * 256] = acc[i];
  out[(size_t)t * ND + 768 + c] = 0.0f;
}

// ---------------- host ----------------
extern "C" void kernel_launch(void* const* d_in, const int* in_sizes, int n_in,
                              void* d_out, int out_size, void* d_ws, size_t ws_size,
                              hipStream_t stream) {
  (void)in_sizes; (void)n_in; (void)ws_size; (void)out_size;
  const float* x  = (const float*)d_in[0];
  const float* wr = (const float*)d_in[1];
  const float* qw = (const float*)d_in[2];
  const float* qbias = (const float*)d_in[3];
  const float* kw = (const float*)d_in[4];
  const float* kbias = (const float*)d_in[5];
  const float* vw = (const float*)d_in[6];
  const float* vbias = (const float*)d_in[7];
  const float* ow = (const float*)d_in[8];
  const float* obias = (const float*)d_in[9];
  const float* w1 = (const float*)d_in[10];
  const float* b1 = (const float*)d_in[11];
  const float* w2 = (const float*)d_in[12];
  const float* b2 = (const float*)d_in[13];
  float* out = (float*)d_out;
  char* ws = (char*)d_ws;

  size_t off = 0;
  auto alloc = [&](size_t bytes) {
    void* p = ws + off;
    off += (bytes + 255) & ~(size_t)255;
    return p;
  };
  float* gate = (float*)alloc((size_t)NTOK * NE * 4);
  int* cnt64s = (int*)alloc(32 * 4);
  int* idx_all = (int*)alloc((size_t)NE * NTOK * 4);
  int* inv = (int*)alloc((size_t)NTOK * 2 * 4);
  ush* xs  = (ush*)alloc((size_t)NTOK * NW * 2);
  ush* wqb = (ush*)alloc((size_t)NE * NW * NW * 2);
  ush* wkb = (ush*)alloc((size_t)NE * NW * NW * 2);
  ush* wvb = (ush*)alloc((size_t)NE * NW * NW * 2);
  ush* wob = (ush*)alloc((size_t)NE * NW * NW * 2);
  ush* w1b = (ush*)alloc((size_t)NE * NF * NW * 2);
  ush* w2b = (ush*)alloc((size_t)NE * NW * NF * 2);
  ush* x1b = (ush*)alloc((size_t)RCAP * NW * 2);
  // arena1: attn {qg, aog} -> ffn {hb}
  char* arena1 = (char*)alloc((size_t)RCAP * NF * 2);          // 86.0 MB
  ush* qg  = (ush*)arena1;                                      // RCAP*768*2 = 16.1 MB
  ush* aog = (ush*)(arena1 + 16121856);                         // RCAP*768*2 (dead before hb written)
  ush* hb  = (ush*)arena1;                                      // ffn phase (after aog consumed)
  // arena2: attn {kg, vtg} -> post {ooP, ffp}
  char* arena2 = (char*)alloc(112852992);
  ush* kg  = (ush*)arena2;                                      // 8*4096*768*2 = 50.3 MB
  ush* vtg = (ush*)(arena2 + 50331648);                         // 50.3 MB
  ush* ooP = (ush*)(arena2 + 16121856);                         // 1 partial 16.1 MB
  ush* ffp = (ush*)(arena2 + 32243712);                         // 2 partials 32.2 MB

  router_kernel<<<dim3(NTOK / 4), 256, 0, stream>>>(x, wr, gate, inv);
  build_index<<<dim3(NE * NB), 1024, 0, stream>>>(gate, cnt64s, idx_all, inv);
  cast_all<<<dim3(288, 9), 256, 0, stream>>>(x, qw, kw, vw, ow, w1, w2,
                                             xs, wqb, wkb, wvb, wob, w1b, w2b);

  // QKV narrow: per-expert 576 blocks (bn 6 x bm 32 x w 3); V^T coalesced via LDS transpose
  qkv_gemm<<<dim3(8 * 576), 256, 0, stream>>>(
      xs, wqb, wkb, wvb, qbias, kbias, vbias, qg, kg, vtg, cnt64s, idx_all);

  // attention: 2-slot pipelined K/V staging, direct AO write; per-expert 384 blocks
  attn2<<<dim3(8 * 384), 256, 0, stream>>>(qg, kg, vtg, aog, cnt64s);

  // o-proj: single K chunk (nsplit=1); per-expert 192 blocks
  csr_gemm<<<dim3(8 * 192), 256, 0, stream>>>(
      aog, wob, obias, ooP, NW, NW, NW, 6, 32, 1, NW * NW, ND, cnt64s);

  rmsnorm_res<<<dim3(RCAP), 256, 0, stream>>>(x, ooP, x1b, cnt64s, idx_all);

  // FFN1 wide (gelu_fast): per-expert 512 blocks (bn 16 x bm 32)
  csr_gemm_w<<<dim3(8 * 512), 256, 0, stream>>>(
      x1b, w1b, b1, hb, NF, NW, NW, 16, NF * NW, NF, cnt64s);

  // FFN2: split-K x2 (K-chunk 2048); per-expert 384 blocks
  csr_gemm<<<dim3(8 * 384), 256, 0, stream>>>(
      hb, w2b, b2, ffp, NW, NF, 2048, 6, 32, 2, NW * NF, ND, cnt64s);

  final_token<<<dim3(NTOK), 256, 0, stream>>>(x1b, ffp, gate, inv, cnt64s, out);
}

// Round 15
// 554.077 us; speedup vs baseline: 1.0364x; 1.0364x over previous
//
#include <hip/hip_runtime.h>
#include <cstdint>

// SlimmableMoE: B=4,S=1024,D=1024,E=8,F=4096,W=768,H=6,HD=128,TOPK=2
#define NE 8
#define NB 4
#define NS 1024
#define ND 1024
#define NF 4096
#define NW 768
#define NH 6
#define NHD 128
#define NTOK 4096   // B*S
#define NBH 24      // B*H
#define RCAP 10496  // compacted-row capacity (max Rtotal=10240 + tile over-read)
#define VSTRIDE ((size_t)NTOK * NW)   // per-expert V^T extent = B*H*HD*S = 3145728
#define EPS 1e-6f

typedef unsigned short ush;
typedef __attribute__((ext_vector_type(8))) short short8;   // 8 bf16 = 4 VGPR
typedef __attribute__((ext_vector_type(4))) float f32x4;
typedef __attribute__((ext_vector_type(4))) unsigned short u16x4;

typedef const __attribute__((address_space(1))) void gvoid_t;
typedef __attribute__((address_space(3))) void lvoid_t;

__device__ __forceinline__ void gload16(const void* g, void* l) {
  __builtin_amdgcn_global_load_lds((gvoid_t*)g, (lvoid_t*)l, 16, 0, 0);
}

__device__ __forceinline__ ush f2b(float f) {
  union { float f; uint32_t u; } x; x.f = f;
  uint32_t r = x.u + 0x7fffu + ((x.u >> 16) & 1u);
  return (ush)(r >> 16);
}
__device__ __forceinline__ float b2f(ush u) {
  union { uint32_t u; float f; } x; x.u = (uint32_t)u << 16;
  return x.f;
}
__device__ __forceinline__ int prefix_sum(const int* __restrict__ c, int n) {
  int s = 0;
#pragma unroll 1
  for (int i = 0; i < n; ++i) s += c[i];
  return s;
}

// ---- pipelined-GEMM LDS packing (validated R9/R10) ----
// vrow u (128 B) holds logical rows u (bytes 0-63) and u+PAIR (bytes 64-127),
// bytes swizzled ^((u&7)<<4). Staging: chunk c, dst = base + c*4096 + tid*16 (linear);
// source row/kbyte from the inverse swizzle.

// ---------------- router: logits->softmax->top2->gate; init inv map ----------------
__global__ __launch_bounds__(256, 4)
void router_kernel(const float* __restrict__ x, const float* __restrict__ wr,
                   float* __restrict__ gate, int* __restrict__ inv) {
  int lane = threadIdx.x & 63, wave = threadIdx.x >> 6;
  int t = blockIdx.x * 4 + wave;
  float acc[NE] = {};
  for (int i = 0; i < 16; ++i) {
    int d = lane + i * 64;
    float xv = x[(size_t)t * ND + d];
    const float* wp = wr + (size_t)d * NE;
    float4 w0 = *(const float4*)wp, w1 = *(const float4*)(wp + 4);
    acc[0] += xv * w0.x; acc[1] += xv * w0.y; acc[2] += xv * w0.z; acc[3] += xv * w0.w;
    acc[4] += xv * w1.x; acc[5] += xv * w1.y; acc[6] += xv * w1.z; acc[7] += xv * w1.w;
  }
#pragma unroll
  for (int e = 0; e < NE; ++e)
    for (int m = 1; m < 64; m <<= 1) acc[e] += __shfl_xor(acc[e], m);
  int i1 = 0; float v1 = acc[0];
#pragma unroll
  for (int e = 1; e < NE; ++e) if (acc[e] > v1) { v1 = acc[e]; i1 = e; }
  int i2 = -1; float v2 = -3.0e38f;
#pragma unroll
  for (int e = 0; e < NE; ++e) if (e != i1 && acc[e] > v2) { v2 = acc[e]; i2 = e; }
  float p2 = __expf(v2 - v1);          // p1 = 1
  float g1 = 1.0f / (1.0f + p2), g2 = p2 / (1.0f + p2);
  if (lane < NE)
    gate[(size_t)t * NE + lane] = (lane == i1) ? g1 : ((lane == i2) ? g2 : 0.0f);
  if (lane < 2) inv[t * 2 + lane] = -1;
}

// ---------------- per-expert routed-token index lists + inverse map ----------------
__global__ __launch_bounds__(1024, 1)
void build_index(const float* __restrict__ gate, int* __restrict__ cnt64s,
                 int* __restrict__ idx_all, int* __restrict__ inv) {
  int e = blockIdx.x >> 2, b = blockIdx.x & 3;
  int s = threadIdx.x, t = b * 1024 + s;
  bool on = gate[(size_t)t * NE + e] > 0.0f;
  idx_all[(e * 4 + b) * 1024 + s] = (b * 1024) | (int)0x80000000;   // pad default
  __shared__ int wsum[16], wbase[16];
  unsigned long long mask = __ballot(on);
  int lane = s & 63, wv = s >> 6;
  if (lane == 0) wsum[wv] = __popcll(mask);
  __syncthreads();
  if (s == 0) {
    int acc = 0;
    for (int i = 0; i < 16; ++i) { wbase[i] = acc; acc += wsum[i]; }
    cnt64s[e * 4 + b] = (acc + 63) & ~63;
  }
  __syncthreads();
  if (on) {
    int pos = wbase[wv] + __popcll(mask & ((1ull << lane) - 1ull));
    idx_all[(e * 4 + b) * 1024 + pos] = t;
    int k = 0;
#pragma unroll
    for (int j = 0; j < NE; ++j) k += (j < e && gate[(size_t)t * NE + j] > 0.0f);
    inv[t * 2 + k] = (e << 12) | pos;
  }
}

// ---------------- all casts f32->bf16 in one launch: y=0..7 expert weights, y=8 xs ----------------
__global__ __launch_bounds__(256, 4)
void cast_all(const float* __restrict__ x,
              const float* __restrict__ qw, const float* __restrict__ kw,
              const float* __restrict__ vw, const float* __restrict__ ow,
              const float* __restrict__ w1, const float* __restrict__ w2,
              ush* __restrict__ xs,
              ush* __restrict__ dq, ush* __restrict__ dk, ush* __restrict__ dv,
              ush* __restrict__ dwo, ush* __restrict__ d1, ush* __restrict__ d2) {
  int y = blockIdx.y;
  if (y == 8) {
    const int n4 = NTOK * NW / 4;
    for (int u = blockIdx.x * 256 + threadIdx.x; u < n4; u += gridDim.x * 256) {
      int r = u / (NW / 4), c = u - r * (NW / 4);
      float4 v = *(const float4*)(x + (size_t)r * ND + c * 4);
      u16x4 o; o.x = f2b(v.x); o.y = f2b(v.y); o.z = f2b(v.z); o.w = f2b(v.w);
      *(u16x4*)(xs + (size_t)u * 4) = o;
    }
    return;
  }
  const int e = y;
  const int Q4 = 147456;   // 768*768/4
  const int W14 = 786432;  // 4096*768/4
  const int total = 4 * Q4 + 2 * W14;
  const float* qe = qw + (size_t)e * ND * ND;
  const float* ke = kw + (size_t)e * ND * ND;
  const float* ve = vw + (size_t)e * ND * ND;
  const float* oe = ow + (size_t)e * ND * ND;
  const float* w1e = w1 + (size_t)e * NF * ND;
  const float* w2e = w2 + (size_t)e * ND * NF;
  ush* dqe = dq + (size_t)e * NW * NW;
  ush* dke = dk + (size_t)e * NW * NW;
  ush* dve = dv + (size_t)e * NW * NW;
  ush* doe = dwo + (size_t)e * NW * NW;
  ush* d1e = d1 + (size_t)e * NF * NW;
  ush* d2e = d2 + (size_t)e * NW * NF;
  for (int u = blockIdx.x * 256 + threadIdx.x; u < total; u += gridDim.x * 256) {
    const float* src; ush* dst; int ldsrc, cols4, rel;
    if (u < 4 * Q4) {
      int which = u / Q4; rel = u - which * Q4;
      src = (which == 0) ? qe : (which == 1) ? ke : (which == 2) ? ve : oe;
      dst = (which == 0) ? dqe : (which == 1) ? dke : (which == 2) ? dve : doe;
      ldsrc = 1024; cols4 = 192;
    } else if (u < 4 * Q4 + W14) {
      rel = u - 4 * Q4; src = w1e; dst = d1e; ldsrc = 1024; cols4 = 192;
    } else {
      rel = u - 4 * Q4 - W14; src = w2e; dst = d2e; ldsrc = 4096; cols4 = 1024;
    }
    int r = rel / cols4, c = rel - r * cols4;
    float4 v = *(const float4*)(src + (size_t)r * ldsrc + (size_t)c * 4);
    u16x4 o; o.x = f2b(v.x); o.y = f2b(v.y); o.z = f2b(v.z); o.w = f2b(v.w);
    *(u16x4*)(dst + (size_t)rel * 4) = o;
  }
}

#define BM 128
#define BN 128

// fast tanh-form gelu (~12 VALU vs ~30 for erff); |err| vs exact <~1e-3
__device__ __forceinline__ float gelu_fast(float v) {
  float u = v * fmaf(0.0356774081f, v * v, 0.7978845608f);
  float p = __expf(2.0f * fabsf(u));               // e^{2|u|} (inf-safe)
  float th = fmaf(-2.0f, __builtin_amdgcn_rcpf(p + 1.0f), 1.0f);
  th = copysignf(th, u);
  return 0.5f * v * (1.0f + th);
}

// staging-geometry (validated R9/R10): vrow u, pair offset PAIR
__device__ __forceinline__ void stage_geom2(int tid, int u, int PAIR, int& row, int& kb) {
  row = u + PAIR * (((tid >> 2) ^ (u >> 2)) & 1);
  kb = ((tid ^ u) & 3) << 4;
}

// ---------------- batched QKV GEMM (narrow 128x128, 3-slot BK=32 pipeline) ----------------
// 1-D grid nwg = 8*576; e = bid&7 (XCD-pinned), wi = bid>>3: bn=wi%6, bm=(wi/6)%32, w=wi/192
// V^T output transposed through LDS (reused pipeline slots) for coalesced writes.
__global__ __launch_bounds__(256, 3)
void qkv_gemm(const ush* __restrict__ A,
              const ush* __restrict__ wqb, const ush* __restrict__ wkb,
              const ush* __restrict__ wvb,
              const float* __restrict__ qbias, const float* __restrict__ kbias,
              const float* __restrict__ vbias,
              ush* __restrict__ qg, ush* __restrict__ kg, ush* __restrict__ vtg,
              const int* __restrict__ cnt64s, const int* __restrict__ idx_all) {
  const int bid = blockIdx.x;
  const int e = bid & 7, wi = bid >> 3;
  const int bn = wi % 6, bm = (wi / 6) % 32, w = wi / 192;
  int sb = 0, cnt = 0;
  if (w == 0) {
    int sec = e * 4 + (bm >> 3);
    cnt = cnt64s[sec];
    if (((bm & 7) * 128) >= cnt) return;
    sb = prefix_sum(cnt64s, sec);
  }
  const ush* Bw = ((w == 0) ? wqb : (w == 1) ? wkb : wvb) + (size_t)e * NW * NW;
  const float* bias = ((w == 0) ? qbias : (w == 1) ? kbias : vbias) + (size_t)e * ND;

  __shared__ __align__(16) char LDS[3 * 16384];

  const int tid = threadIdx.x, lane = tid & 63, wave = tid >> 6;
  const int lr = lane & 15, lg = lane >> 4;
  const int wr = wave >> 1, wc = wave & 1;

  size_t srcOff[4];
#pragma unroll
  for (int c = 0; c < 4; ++c) {
    int u = (c & 1) * 32 + (tid >> 3), row, kb;
    stage_geom2(tid, u, 64, row, kb);
    int gRow;
    if (c < 2) {
      if (w == 0) {
        int lrow = (bm & 7) * 128 + row;
        gRow = idx_all[(e * 4 + (bm >> 3)) * 1024 + lrow] & 0x7fffffff;
      } else {
        gRow = bm * BM + row;
      }
    } else {
      gRow = bn * BN + row;
    }
    srcOff[c] = (size_t)gRow * (NW * 2) + kb;
  }

  int offA[4], offB[4];
#pragma unroll
  for (int i = 0; i < 4; ++i) {
    offA[i] = (i * 16 + lr) * 128 + (((wr << 6) | (lg << 4)) ^ ((lr & 7) << 4));
    offB[i] = (i * 16 + lr) * 128 + (((wc << 6) | (lg << 4)) ^ ((lr & 7) << 4)) + 8192;
  }

  auto stg = [&](int slot, int kt) {
    size_t kOff = (size_t)kt * 64;
    char* dst = LDS + slot * 16384;
#pragma unroll
    for (int c = 0; c < 4; ++c) {
      const char* src = (c < 2) ? (const char*)A + srcOff[c] + kOff
                                : (const char*)Bw + srcOff[c] + kOff;
      gload16(src, dst + c * 4096 + tid * 16);
    }
  };

  f32x4 acc[4][4] = {};
  const int nkt = NW / 32;   // 24
  stg(0, 0); stg(1, 1);
  asm volatile("s_waitcnt vmcnt(4)" ::: "memory");
  asm volatile("s_barrier" ::: "memory");
  int slot = 0;
  for (int kt = 0; kt < nkt; ++kt) {
    int s2 = slot + 2; if (s2 >= 3) s2 -= 3;
    bool more = (kt + 2 < nkt);
    if (more) stg(s2, kt + 2);
    const char* base = LDS + slot * 16384;
    short8 af[4], bfr[4];
#pragma unroll
    for (int i = 0; i < 4; ++i) {
      af[i] = *(const short8*)(base + offA[i]);
      bfr[i] = *(const short8*)(base + offB[i]);
    }
    __builtin_amdgcn_s_setprio(1);
#pragma unroll
    for (int i = 0; i < 4; ++i)
#pragma unroll
      for (int j = 0; j < 4; ++j)
        acc[i][j] = __builtin_amdgcn_mfma_f32_16x16x32_bf16(af[i], bfr[j], acc[i][j], 0, 0, 0);
    __builtin_amdgcn_s_setprio(0);
    if (more) asm volatile("s_waitcnt vmcnt(4)" ::: "memory");
    else      asm volatile("s_waitcnt vmcnt(0)" ::: "memory");
    asm volatile("s_barrier" ::: "memory");
    slot = (slot == 2) ? 0 : slot + 1;
  }

  if (w == 2) {
    // V^T: transpose through LDS (pipeline slots dead after final barrier).
    // Tile T[d][s]: d=0..127 rows of 256B, byte addr = d*256 + ((s*2) ^ ((d&15)<<4)).
#pragma unroll
    for (int i = 0; i < 4; ++i) {
      int sl = wr * 64 + i * 16 + lg * 4;          // section-local s
#pragma unroll
      for (int j = 0; j < 4; ++j) {
        int d = wc * 64 + j * 16 + lr;
        float bb = bias[bn * BN + d];
        u16x4 wv_;
#pragma unroll
        for (int r = 0; r < 4; ++r) wv_[r] = f2b(acc[i][j][r] + bb);
        *(u16x4*)(LDS + d * 256 + ((sl * 2) ^ ((d & 15) << 4))) = wv_;
      }
    }
    __syncthreads();
    // stream out: thread -> (d = tid>>1, s-half = (tid&1)*64); 8 x 16B coalesced stores
    int d = tid >> 1, sh = (tid & 1) * 64;
    int b_ = bm >> 3, s0b = (bm & 7) * 128;
    ush* gdst = vtg + (size_t)e * VSTRIDE +
                ((size_t)(b_ * NH + bn) * NHD + d) * NS + s0b + sh;
#pragma unroll
    for (int c = 0; c < 8; ++c) {
      short8 v = *(const short8*)(LDS + d * 256 + (((sh + c * 8) * 2) ^ ((d & 15) << 4)));
      *(short8*)(gdst + c * 8) = v;
    }
    return;
  }

#pragma unroll
  for (int i = 0; i < 4; ++i) {
    int lm16 = (bm & 7) * 128 + wr * 64 + i * 16;            // Q: section-local 16-row group
    int m0 = bm * BM + wr * 64 + i * 16 + lg * 4;            // dense row
#pragma unroll
    for (int j = 0; j < 4; ++j) {
      int n = bn * BN + wc * 64 + j * 16 + lr;
      float bb = bias[n];
      if (w == 0) {
        if (lm16 < cnt) {
          int grow = sb + lm16 + lg * 4;
#pragma unroll
          for (int r = 0; r < 4; ++r)
            qg[(size_t)(grow + r) * NW + n] = f2b(acc[i][j][r] + bb);
        }
      } else {
        ush* o = kg + (size_t)e * NTOK * NW;
#pragma unroll
        for (int r = 0; r < 4; ++r)
          o[(size_t)(m0 + r) * NW + n] = f2b(acc[i][j][r] + bb);
      }
    }
  }
}

// ---------------- batched flash attention (R13-proven): full KV sweep, direct AO write ----------------
// 1-D grid 8*384; e = bid&7; wi = bid>>3: qb = wi&15, bh = wi>>4 in [0,24)
__global__ __launch_bounds__(256, 3)
void attn2(const ush* __restrict__ Qg, const ush* __restrict__ Kg,
           const ush* __restrict__ VTg, ush* __restrict__ ao,
           const int* __restrict__ cnt64s) {
  const int bid = blockIdx.x;
  const int e = bid & 7, wi = bid >> 3;
  const int qb = wi & 15, bh = wi >> 4;
  const int b = bh / NH, h = bh % NH;
  const int sec = e * 4 + b;
  const int cnt = cnt64s[sec];
  if (qb * 64 >= cnt) return;
  const int sb = prefix_sum(cnt64s, sec);

  __shared__ __align__(16) ush Ks[64 * 128];
  __shared__ __align__(16) ush VTs[128 * 64];
  __shared__ __align__(16) ush Ps[4 * 16 * 64];

  const int tid = threadIdx.x, lane = tid & 63, wave = tid >> 6;
  const int lr = lane & 15, lg = lane >> 4;
  const float cexp = 1.4426950408889634f / sqrtf((float)NHD);

  const ush* Ke = Kg + (size_t)e * NTOK * NW;
  const ush* Ve = VTg + (size_t)e * VSTRIDE;

  int growq = sb + qb * 64 + wave * 16 + lr;
  short8 qf[4];
#pragma unroll
  for (int kk = 0; kk < 4; ++kk)
    qf[kk] = *(const short8*)(Qg + (size_t)growq * NW + h * NHD + kk * 32 + lg * 8);

  f32x4 accv[8] = {};
  float mr[4] = {-3.0e38f, -3.0e38f, -3.0e38f, -3.0e38f};
  float ls[4] = {};

  for (int kt = 0; kt < 16; ++kt) {   // 16 x 64 keys = all 1024
    __syncthreads();
#pragma unroll
    for (int p = 0; p < 4; ++p) {
      int o = p * 4096 + tid * 16;
      int row = o >> 8, cb = o & 255;
      gload16((const char*)Ke + ((size_t)(b * NS + kt * 64 + row) * NW + h * NHD) * 2 +
                  (cb ^ ((row & 7) << 4)),
              (char*)Ks + o);
    }
#pragma unroll
    for (int p = 0; p < 4; ++p) {
      int o = p * 4096 + tid * 16;
      int d = o >> 7, cb = o & 127;
      gload16((const char*)Ve + ((size_t)((b * NH + h) * NHD + d) * NS + kt * 64) * 2 +
                  (cb ^ ((d & 7) << 4)),
              (char*)VTs + o);
    }
    __syncthreads();

    f32x4 s[4] = {};
    __builtin_amdgcn_s_setprio(1);
#pragma unroll
    for (int kg2 = 0; kg2 < 4; ++kg2)
#pragma unroll
      for (int kk = 0; kk < 4; ++kk) {
        int row = kg2 * 16 + lr;
        short8 kf = *(const short8*)((const char*)Ks + row * 256 +
                                     ((kk * 64 + lg * 16) ^ ((row & 7) << 4)));
        s[kg2] = __builtin_amdgcn_mfma_f32_16x16x32_bf16(qf[kk], kf, s[kg2], 0, 0, 0);
      }
    __builtin_amdgcn_s_setprio(0);

    float mt[4];
#pragma unroll
    for (int r = 0; r < 4; ++r) {
      float m0 = fmaxf(fmaxf(s[0][r], s[1][r]), fmaxf(s[2][r], s[3][r]));
#pragma unroll
      for (int mm = 1; mm < 16; mm <<= 1) m0 = fmaxf(m0, __shfl_xor(m0, mm));
      mt[r] = m0;
    }
    bool need = (mt[0] > mr[0] + 8.f) || (mt[1] > mr[1] + 8.f) ||
                (mt[2] > mr[2] + 8.f) || (mt[3] > mr[3] + 8.f);
    if (__any(need)) {
#pragma unroll
      for (int r = 0; r < 4; ++r) {
        float mn = fmaxf(mr[r], mt[r]);
        float sc = exp2f((mr[r] - mn) * cexp);
        mr[r] = mn; ls[r] *= sc;
#pragma unroll
        for (int dg = 0; dg < 8; ++dg) accv[dg][r] *= sc;
      }
    }

    char* pw = (char*)Ps + wave * 2048;
#pragma unroll
    for (int kg2 = 0; kg2 < 4; ++kg2)
#pragma unroll
      for (int r = 0; r < 4; ++r) {
        float p = exp2f((s[kg2][r] - mr[r]) * cexp);
        ls[r] += p;
        int row = lg * 4 + r;
        *(ush*)(pw + row * 128 + (((kg2 * 16 + lr) * 2) ^ ((row & 7) << 4))) = f2b(p);
      }
    short8 pf[2];
#pragma unroll
    for (int kk2 = 0; kk2 < 2; ++kk2)
      pf[kk2] = *(const short8*)(pw + lr * 128 + ((kk2 * 64 + lg * 16) ^ ((lr & 7) << 4)));

    __builtin_amdgcn_s_setprio(1);
#pragma unroll
    for (int dg = 0; dg < 8; ++dg) {
      int d = dg * 16 + lr;
#pragma unroll
      for (int kk2 = 0; kk2 < 2; ++kk2) {
        short8 vf = *(const short8*)((const char*)VTs + d * 128 +
                                     ((kk2 * 64 + lg * 16) ^ ((d & 7) << 4)));
        accv[dg] = __builtin_amdgcn_mfma_f32_16x16x32_bf16(pf[kk2], vf, accv[dg], 0, 0, 0);
      }
    }
    __builtin_amdgcn_s_setprio(0);
  }

  // reduce l across row group, normalize, write AO directly
#pragma unroll
  for (int r = 0; r < 4; ++r)
#pragma unroll
    for (int mm = 1; mm < 16; mm <<= 1) ls[r] += __shfl_xor(ls[r], mm);

#pragma unroll
  for (int r = 0; r < 4; ++r) {
    int growr = sb + qb * 64 + wave * 16 + lg * 4 + r;
    float inv_ = 1.0f / ls[r];
#pragma unroll
    for (int dg = 0; dg < 8; ++dg)
      ao[(size_t)growr * NW + h * NHD + dg * 16 + lr] = f2b(accv[dg][r] * inv_);
  }
}

// ---------------- CSR GEMM wide: 128x256 tile, 4x8 acc, 3-slot BK=32 pipeline (FFN1) ----------------
__global__ __launch_bounds__(256, 2)
void csr_gemm_w(const ush* __restrict__ A, const ush* __restrict__ Ball,
                const float* __restrict__ biasAll, ush* __restrict__ out,
                int N, int Kld, int klen, int nbn,
                int strideBe, int biasStride,
                const int* __restrict__ cnt64s) {
  const int bid = blockIdx.x;
  const int e = bid & 7, wi = bid >> 3;
  const int bn = wi % nbn, bm = wi / nbn;
  const int Re = cnt64s[e * 4] + cnt64s[e * 4 + 1] + cnt64s[e * 4 + 2] + cnt64s[e * 4 + 3];
  if (bm * BM >= Re) return;
  const int ebase = prefix_sum(cnt64s, e * 4);
  const ush* Bw = Ball + (size_t)e * strideBe;
  const float* bias = biasAll + (size_t)e * biasStride;

  __shared__ __align__(16) char LDS[3 * 24576];

  const int tid = threadIdx.x, lane = tid & 63, wave = tid >> 6;
  const int lr = lane & 15, lg = lane >> 4;
  const int wr = wave >> 1, wc = wave & 1;

  size_t srcOff[6];
#pragma unroll
  for (int c = 0; c < 2; ++c) {
    int u = c * 32 + (tid >> 3), row, kb;
    stage_geom2(tid, u, 64, row, kb);
    srcOff[c] = (size_t)(ebase + bm * BM + row) * (Kld * 2) + kb;
  }
#pragma unroll
  for (int c = 0; c < 4; ++c) {
    int u = c * 32 + (tid >> 3), row, kb;
    stage_geom2(tid, u, 128, row, kb);
    srcOff[2 + c] = (size_t)(bn * 256 + row) * (Kld * 2) + kb;
  }

  int offA[4], offB[8];
#pragma unroll
  for (int i = 0; i < 4; ++i)
    offA[i] = (i * 16 + lr) * 128 + (((wr << 6) | (lg << 4)) ^ ((lr & 7) << 4));
#pragma unroll
  for (int j = 0; j < 8; ++j)
    offB[j] = (j * 16 + lr) * 128 + (((wc << 6) | (lg << 4)) ^ ((lr & 7) << 4)) + 8192;

  auto stg = [&](int slot, int kt) {
    size_t kOff = (size_t)kt * 64;
    char* dst = LDS + slot * 24576;
#pragma unroll
    for (int c = 0; c < 2; ++c)
      gload16((const char*)A + srcOff[c] + kOff, dst + c * 4096 + tid * 16);
#pragma unroll
    for (int c = 0; c < 4; ++c)
      gload16((const char*)Bw + srcOff[2 + c] + kOff, dst + 8192 + c * 4096 + tid * 16);
  };

  f32x4 acc[4][8] = {};
  const int nkt = klen / 32;
  stg(0, 0); stg(1, 1);
  asm volatile("s_waitcnt vmcnt(6)" ::: "memory");
  asm volatile("s_barrier" ::: "memory");
  int slot = 0;
  for (int kt = 0; kt < nkt; ++kt) {
    int s2 = slot + 2; if (s2 >= 3) s2 -= 3;
    bool more = (kt + 2 < nkt);
    if (more) stg(s2, kt + 2);
    const char* base = LDS + slot * 24576;
    short8 af[4], bfr[8];
#pragma unroll
    for (int i = 0; i < 4; ++i) af[i] = *(const short8*)(base + offA[i]);
#pragma unroll
    for (int j = 0; j < 8; ++j) bfr[j] = *(const short8*)(base + offB[j]);
    __builtin_amdgcn_s_setprio(1);
#pragma unroll
    for (int i = 0; i < 4; ++i)
#pragma unroll
      for (int j = 0; j < 8; ++j)
        acc[i][j] = __builtin_amdgcn_mfma_f32_16x16x32_bf16(af[i], bfr[j], acc[i][j], 0, 0, 0);
    __builtin_amdgcn_s_setprio(0);
    if (more) asm volatile("s_waitcnt vmcnt(6)" ::: "memory");
    else      asm volatile("s_waitcnt vmcnt(0)" ::: "memory");
    asm volatile("s_barrier" ::: "memory");
    slot = (slot == 2) ? 0 : slot + 1;
  }

#pragma unroll
  for (int i = 0; i < 4; ++i) {
    int lm16 = bm * BM + wr * 64 + i * 16;
    if (lm16 >= Re) continue;
#pragma unroll
    for (int j = 0; j < 8; ++j) {
      int n = bn * 256 + wc * 128 + j * 16 + lr;
      float bb = bias[n];
      int row0 = ebase + lm16 + lg * 4;
#pragma unroll
      for (int r = 0; r < 4; ++r)
        out[(size_t)(row0 + r) * N + n] = f2b(gelu_fast(acc[i][j][r] + bb));
    }
  }
}

// ---------------- CSR GEMM (128x128, 3-slot BK=32 pipeline; o-proj & FFN2) ----------------
__global__ __launch_bounds__(256, 3)
void csr_gemm(const ush* __restrict__ A, const ush* __restrict__ Ball,
              const float* __restrict__ biasAll, ush* __restrict__ out,
              int N, int Kld, int klen, int nbn, int nbm, int nsplit,
              int strideBe, int biasStride,
              const int* __restrict__ cnt64s) {
  const int bid = blockIdx.x;
  const int e = bid & 7, wi = bid >> 3;
  const int bn = wi % nbn, bm = (wi / nbn) % nbm, s = wi / (nbn * nbm);
  const int Re = cnt64s[e * 4] + cnt64s[e * 4 + 1] + cnt64s[e * 4 + 2] + cnt64s[e * 4 + 3];
  if (bm * BM >= Re) return;
  const int ebase = prefix_sum(cnt64s, e * 4);
  const ush* Bw = Ball + (size_t)e * strideBe;
  const float* bias = (s == 0) ? biasAll + (size_t)e * biasStride : nullptr;
  const int koff = s * klen;
  ush* outp = out + (size_t)s * RCAP * N;

  __shared__ __align__(16) char LDS[3 * 16384];

  const int tid = threadIdx.x, lane = tid & 63, wave = tid >> 6;
  const int lr = lane & 15, lg = lane >> 4;
  const int wr = wave >> 1, wc = wave & 1;

  size_t srcOff[4];
#pragma unroll
  for (int c = 0; c < 4; ++c) {
    int u = (c & 1) * 32 + (tid >> 3), row, kb;
    stage_geom2(tid, u, 64, row, kb);
    int gRow = (c < 2) ? (ebase + bm * BM + row) : (bn * BN + row);
    srcOff[c] = (size_t)gRow * (Kld * 2) + (size_t)koff * 2 + kb;
  }

  int offA[4], offB[4];
#pragma unroll
  for (int i = 0; i < 4; ++i) {
    offA[i] = (i * 16 + lr) * 128 + (((wr << 6) | (lg << 4)) ^ ((lr & 7) << 4));
    offB[i] = (i * 16 + lr) * 128 + (((wc << 6) | (lg << 4)) ^ ((lr & 7) << 4)) + 8192;
  }

  auto stg = [&](int slot, int kt) {
    size_t kOff = (size_t)kt * 64;
    char* dst = LDS + slot * 16384;
#pragma unroll
    for (int c = 0; c < 4; ++c) {
      const char* src = (c < 2) ? (const char*)A + srcOff[c] + kOff
                                : (const char*)Bw + srcOff[c] + kOff;
      gload16(src, dst + c * 4096 + tid * 16);
    }
  };

  f32x4 acc[4][4] = {};
  const int nkt = klen / 32;
  stg(0, 0); stg(1, 1);
  asm volatile("s_waitcnt vmcnt(4)" ::: "memory");
  asm volatile("s_barrier" ::: "memory");
  int slot = 0;
  for (int kt = 0; kt < nkt; ++kt) {
    int s2 = slot + 2; if (s2 >= 3) s2 -= 3;
    bool more = (kt + 2 < nkt);
    if (more) stg(s2, kt + 2);
    const char* base = LDS + slot * 16384;
    short8 af[4], bfr[4];
#pragma unroll
    for (int i = 0; i < 4; ++i) {
      af[i] = *(const short8*)(base + offA[i]);
      bfr[i] = *(const short8*)(base + offB[i]);
    }
    __builtin_amdgcn_s_setprio(1);
#pragma unroll
    for (int i = 0; i < 4; ++i)
#pragma unroll
      for (int j = 0; j < 4; ++j)
        acc[i][j] = __builtin_amdgcn_mfma_f32_16x16x32_bf16(af[i], bfr[j], acc[i][j], 0, 0, 0);
    __builtin_amdgcn_s_setprio(0);
    if (more) asm volatile("s_waitcnt vmcnt(4)" ::: "memory");
    else      asm volatile("s_waitcnt vmcnt(0)" ::: "memory");
    asm volatile("s_barrier" ::: "memory");
    slot = (slot == 2) ? 0 : slot + 1;
  }

#pragma unroll
  for (int i = 0; i < 4; ++i) {
    int lm16 = bm * BM + wr * 64 + i * 16;
    if (lm16 >= Re) continue;                  // cross-expert guard (Re % 64 == 0)
#pragma unroll
    for (int j = 0; j < 4; ++j) {
      int n = bn * BN + wc * 64 + j * 16 + lr;
      float bb = bias ? bias[n] : 0.0f;
      int row0 = ebase + lm16 + lg * 4;
#pragma unroll
      for (int r = 0; r < 4; ++r)
        outp[(size_t)(row0 + r) * N + n] = f2b(acc[i][j][r] + bb);
    }
  }
}

// ---------------- residual + RMSNorm over compacted rows (single o-proj partial) ----------------
__global__ __launch_bounds__(256, 4)
void rmsnorm_res(const float* __restrict__ x, const ush* __restrict__ ooP,
                 ush* __restrict__ x1b, const int* __restrict__ cnt64s,
                 const int* __restrict__ idx_all) {
  int r = blockIdx.x;
  int base = 0, sec = -1, loc = 0;
#pragma unroll 1
  for (int i = 0; i < 32; ++i) {
    int cc = cnt64s[i];
    if (sec < 0 && r < base + cc) { sec = i; loc = r - base; }
    base += cc;
  }
  if (sec < 0) return;
  int t = idx_all[sec * 1024 + loc] & 0x7fffffff;
  __shared__ float red[4];
  int c = threadIdx.x, lane = c & 63, wave = c >> 6;
  float v[3]; float ss = 0.0f;
#pragma unroll
  for (int i = 0; i < 3; ++i) {
    int col = c + i * 256;
    float a = x[(size_t)t * ND + col] + b2f(ooP[(size_t)r * NW + col]);
    v[i] = a; ss += a * a;
  }
#pragma unroll
  for (int m = 1; m < 64; m <<= 1) ss += __shfl_xor(ss, m);
  if (lane == 0) red[wave] = ss;
  __syncthreads();
  float tot = red[0] + red[1] + red[2] + red[3];
  float scale = rsqrtf(tot / (float)NW + EPS);
#pragma unroll
  for (int i = 0; i < 3; ++i) {
    int col = c + i * 256;
    x1b[(size_t)r * NW + col] = f2b(v[i] * scale);
  }
}

// ---------------- final: per token, gather both experts, rmsnorm, gate-sum (1 ffp partial) ----------------
__global__ __launch_bounds__(256, 4)
void final_token(const ush* __restrict__ x1b, const ush* __restrict__ ffp,
                 const float* __restrict__ gate, const int* __restrict__ inv,
                 const int* __restrict__ cnt64s, float* __restrict__ out) {
  int t = blockIdx.x, c = threadIdx.x, lane = c & 63, wave = c >> 6;
  __shared__ float red[4];
  float acc[3] = {0.0f, 0.0f, 0.0f};
#pragma unroll 1
  for (int k = 0; k < 2; ++k) {
    int v = inv[t * 2 + k];
    if (v >= 0) {
      int e = v >> 12, pos = v & 0xfff;
      int b = t >> 10;
      int grow = prefix_sum(cnt64s, e * 4 + b) + pos;
      float g = gate[(size_t)t * NE + e];
      float vv[3]; float ss = 0.0f;
#pragma unroll
      for (int i = 0; i < 3; ++i) {
        int col = c + i * 256;
        float a = b2f(x1b[(size_t)grow * NW + col]) + b2f(ffp[(size_t)grow * NW + col]);
        vv[i] = a; ss += a * a;
      }
#pragma unroll
      for (int m = 1; m < 64; m <<= 1) ss += __shfl_xor(ss, m);
      if (lane == 0) red[wave] = ss;
      __syncthreads();
      float tot = red[0] + red[1] + red[2] + red[3];
      float scale = rsqrtf(tot / (float)NW + EPS) * g;
#pragma unroll
      for (int i = 0; i < 3; ++i) acc[i] += vv[i] * scale;
      __syncthreads();
    }
  }
#pragma unroll
  for (int i = 0; i < 3; ++i) out[(size_t)t * ND + c + i * 256] = acc[i];
  out[(size_t)t * ND + 768 + c] = 0.0f;
}

// ---------------- host ----------------
extern "C" void kernel_launch(void* const* d_in, const int* in_sizes, int n_in,
                              void* d_out, int out_size, void* d_ws, size_t ws_size,
                              hipStream_t stream) {
  (void)in_sizes; (void)n_in; (void)ws_size; (void)out_size;
  const float* x  = (const float*)d_in[0];
  const float* wr = (const float*)d_in[1];
  const float* qw = (const float*)d_in[2];
  const float* qbias = (const float*)d_in[3];
  const float* kw = (const float*)d_in[4];
  const float* kbias = (const float*)d_in[5];
  const float* vw = (const float*)d_in[6];
  const float* vbias = (const float*)d_in[7];
  const float* ow = (const float*)d_in[8];
  const float* obias = (const float*)d_in[9];
  const float* w1 = (const float*)d_in[10];
  const float* b1 = (const float*)d_in[11];
  const float* w2 = (const float*)d_in[12];
  const float* b2 = (const float*)d_in[13];
  float* out = (float*)d_out;
  char* ws = (char*)d_ws;

  size_t off = 0;
  auto alloc = [&](size_t bytes) {
    void* p = ws + off;
    off += (bytes + 255) & ~(size_t)255;
    return p;
  };
  float* gate = (float*)alloc((size_t)NTOK * NE * 4);
  int* cnt64s = (int*)alloc(32 * 4);
  int* idx_all = (int*)alloc((size_t)NE * NTOK * 4);
  int* inv = (int*)alloc((size_t)NTOK * 2 * 4);
  ush* xs  = (ush*)alloc((size_t)NTOK * NW * 2);
  ush* wqb = (ush*)alloc((size_t)NE * NW * NW * 2);
  ush* wkb = (ush*)alloc((size_t)NE * NW * NW * 2);
  ush* wvb = (ush*)alloc((size_t)NE * NW * NW * 2);
  ush* wob = (ush*)alloc((size_t)NE * NW * NW * 2);
  ush* w1b = (ush*)alloc((size_t)NE * NF * NW * 2);
  ush* w2b = (ush*)alloc((size_t)NE * NW * NF * 2);
  ush* x1b = (ush*)alloc((size_t)RCAP * NW * 2);
  // arena1: attn {qg, aog} -> ffn {hb}
  char* arena1 = (char*)alloc((size_t)RCAP * NF * 2);          // 86.0 MB
  ush* qg  = (ush*)arena1;                                      // RCAP*768*2 = 16.1 MB
  ush* aog = (ush*)(arena1 + 16121856);                         // RCAP*768*2 (dead before hb written)
  ush* hb  = (ush*)arena1;                                      // ffn phase (after aog consumed)
  // arena2: attn {kg, vtg} -> post {ooP, ffp}
  char* arena2 = (char*)alloc(112852992);
  ush* kg  = (ush*)arena2;                                      // 8*4096*768*2 = 50.3 MB
  ush* vtg = (ush*)(arena2 + 50331648);                         // 50.3 MB
  ush* ooP = (ush*)(arena2 + 16121856);                         // 1 partial 16.1 MB
  ush* ffp = (ush*)(arena2 + 32243712);                         // 1 partial 16.1 MB

  router_kernel<<<dim3(NTOK / 4), 256, 0, stream>>>(x, wr, gate, inv);
  build_index<<<dim3(NE * NB), 1024, 0, stream>>>(gate, cnt64s, idx_all, inv);
  cast_all<<<dim3(288, 9), 256, 0, stream>>>(x, qw, kw, vw, ow, w1, w2,
                                             xs, wqb, wkb, wvb, wob, w1b, w2b);

  // QKV narrow: per-expert 576 blocks (bn 6 x bm 32 x w 3); V^T coalesced via LDS transpose
  qkv_gemm<<<dim3(8 * 576), 256, 0, stream>>>(
      xs, wqb, wkb, wvb, qbias, kbias, vbias, qg, kg, vtg, cnt64s, idx_all);

  // attention (R13 structure): full KV sweep, direct AO write; per-expert 384 blocks
  attn2<<<dim3(8 * 384), 256, 0, stream>>>(qg, kg, vtg, aog, cnt64s);

  // o-proj: single K chunk; per-expert 192 blocks
  csr_gemm<<<dim3(8 * 192), 256, 0, stream>>>(
      aog, wob, obias, ooP, NW, NW, NW, 6, 32, 1, NW * NW, ND, cnt64s);

  rmsnorm_res<<<dim3(RCAP), 256, 0, stream>>>(x, ooP, x1b, cnt64s, idx_all);

  // FFN1 wide (gelu_fast): per-expert 512 blocks (bn 16 x bm 32)
  csr_gemm_w<<<dim3(8 * 512), 256, 0, stream>>>(
      x1b, w1b, b1, hb, NF, NW, NW, 16, NF * NW, NF, cnt64s);

  // FFN2: single K chunk (128-step pipeline); per-expert 192 blocks
  csr_gemm<<<dim3(8 * 192), 256, 0, stream>>>(
      hb, w2b, b2, ffp, NW, NF, NF, 6, 32, 1, NW * NF, ND, cnt64s);

  final_token<<<dim3(NTOK), 256, 0, stream>>>(x1b, ffp, gate, inv, cnt64s, out);
}

// Round 16
// 545.291 us; speedup vs baseline: 1.0531x; 1.0161x over previous
//
#include <hip/hip_runtime.h>
#include <cstdint>

// SlimmableMoE: B=4,S=1024,D=1024,E=8,F=4096,W=768,H=6,HD=128,TOPK=2
#define NE 8
#define NB 4
#define NS 1024
#define ND 1024
#define NF 4096
#define NW 768
#define NH 6
#define NHD 128
#define NTOK 4096   // B*S
#define NBH 24      // B*H
#define RCAP 10496  // compacted-row capacity (max Rtotal=10240 + tile over-read)
#define VSTRIDE ((size_t)NTOK * NW)   // per-expert V^T extent = B*H*HD*S = 3145728
#define EPS 1e-6f

typedef unsigned short ush;
typedef __attribute__((ext_vector_type(8))) short short8;   // 8 bf16 = 4 VGPR
typedef __attribute__((ext_vector_type(4))) float f32x4;
typedef __attribute__((ext_vector_type(4))) unsigned short u16x4;

typedef const __attribute__((address_space(1))) void gvoid_t;
typedef __attribute__((address_space(3))) void lvoid_t;

__device__ __forceinline__ void gload16(const void* g, void* l) {
  __builtin_amdgcn_global_load_lds((gvoid_t*)g, (lvoid_t*)l, 16, 0, 0);
}

__device__ __forceinline__ ush f2b(float f) {
  union { float f; uint32_t u; } x; x.f = f;
  uint32_t r = x.u + 0x7fffu + ((x.u >> 16) & 1u);
  return (ush)(r >> 16);
}
__device__ __forceinline__ float b2f(ush u) {
  union { uint32_t u; float f; } x; x.u = (uint32_t)u << 16;
  return x.f;
}
__device__ __forceinline__ int prefix_sum(const int* __restrict__ c, int n) {
  int s = 0;
#pragma unroll 1
  for (int i = 0; i < n; ++i) s += c[i];
  return s;
}

// ---- pipelined-GEMM LDS packing (validated R9/R10) ----
// vrow u (128 B) holds logical rows u (bytes 0-63) and u+PAIR (bytes 64-127),
// bytes swizzled ^((u&7)<<4). Staging: chunk c, dst = base + c*4096 + tid*16 (linear);
// source row/kbyte from the inverse swizzle.

// ---------------- router: logits->softmax->top2->gate; init inv map ----------------
__global__ __launch_bounds__(256, 4)
void router_kernel(const float* __restrict__ x, const float* __restrict__ wr,
                   float* __restrict__ gate, int* __restrict__ inv) {
  int lane = threadIdx.x & 63, wave = threadIdx.x >> 6;
  int t = blockIdx.x * 4 + wave;
  float acc[NE] = {};
  for (int i = 0; i < 16; ++i) {
    int d = lane + i * 64;
    float xv = x[(size_t)t * ND + d];
    const float* wp = wr + (size_t)d * NE;
    float4 w0 = *(const float4*)wp, w1 = *(const float4*)(wp + 4);
    acc[0] += xv * w0.x; acc[1] += xv * w0.y; acc[2] += xv * w0.z; acc[3] += xv * w0.w;
    acc[4] += xv * w1.x; acc[5] += xv * w1.y; acc[6] += xv * w1.z; acc[7] += xv * w1.w;
  }
#pragma unroll
  for (int e = 0; e < NE; ++e)
    for (int m = 1; m < 64; m <<= 1) acc[e] += __shfl_xor(acc[e], m);
  int i1 = 0; float v1 = acc[0];
#pragma unroll
  for (int e = 1; e < NE; ++e) if (acc[e] > v1) { v1 = acc[e]; i1 = e; }
  int i2 = -1; float v2 = -3.0e38f;
#pragma unroll
  for (int e = 0; e < NE; ++e) if (e != i1 && acc[e] > v2) { v2 = acc[e]; i2 = e; }
  float p2 = __expf(v2 - v1);          // p1 = 1
  float g1 = 1.0f / (1.0f + p2), g2 = p2 / (1.0f + p2);
  if (lane < NE)
    gate[(size_t)t * NE + lane] = (lane == i1) ? g1 : ((lane == i2) ? g2 : 0.0f);
  if (lane < 2) inv[t * 2 + lane] = -1;
}

// ---------------- per-expert routed-token index lists + inverse map ----------------
__global__ __launch_bounds__(1024, 1)
void build_index(const float* __restrict__ gate, int* __restrict__ cnt64s,
                 int* __restrict__ idx_all, int* __restrict__ inv) {
  int e = blockIdx.x >> 2, b = blockIdx.x & 3;
  int s = threadIdx.x, t = b * 1024 + s;
  bool on = gate[(size_t)t * NE + e] > 0.0f;
  idx_all[(e * 4 + b) * 1024 + s] = (b * 1024) | (int)0x80000000;   // pad default
  __shared__ int wsum[16], wbase[16];
  unsigned long long mask = __ballot(on);
  int lane = s & 63, wv = s >> 6;
  if (lane == 0) wsum[wv] = __popcll(mask);
  __syncthreads();
  if (s == 0) {
    int acc = 0;
    for (int i = 0; i < 16; ++i) { wbase[i] = acc; acc += wsum[i]; }
    cnt64s[e * 4 + b] = (acc + 63) & ~63;
  }
  __syncthreads();
  if (on) {
    int pos = wbase[wv] + __popcll(mask & ((1ull << lane) - 1ull));
    idx_all[(e * 4 + b) * 1024 + pos] = t;
    int k = 0;
#pragma unroll
    for (int j = 0; j < NE; ++j) k += (j < e && gate[(size_t)t * NE + j] > 0.0f);
    inv[t * 2 + k] = (e << 12) | pos;
  }
}

// ---------------- all casts f32->bf16: compile-time divisors per phase ----------------
// y=0..7: expert e weights (3 phases); y=8: xs
__global__ __launch_bounds__(256, 4)
void cast_all(const float* __restrict__ x,
              const float* __restrict__ qw, const float* __restrict__ kw,
              const float* __restrict__ vw, const float* __restrict__ ow,
              const float* __restrict__ w1, const float* __restrict__ w2,
              ush* __restrict__ xs,
              ush* __restrict__ dq, ush* __restrict__ dk, ush* __restrict__ dv,
              ush* __restrict__ dwo, ush* __restrict__ d1, ush* __restrict__ d2) {
  const int y = blockIdx.y;
  const int step = gridDim.x * 256;
  int u0 = blockIdx.x * 256 + threadIdx.x;
  if (y == 8) {
    const int n4 = NTOK * NW / 4;   // x slice: rows 4096, cols 0..768 of 1024
    for (int u = u0; u < n4; u += step) {
      int r = u / 192, c = u - r * 192;             // const divisor -> magic mul
      float4 v = *(const float4*)(x + (size_t)r * ND + c * 4);
      u16x4 o; o.x = f2b(v.x); o.y = f2b(v.y); o.z = f2b(v.z); o.w = f2b(v.w);
      *(u16x4*)(xs + (size_t)u * 4) = o;
    }
    return;
  }
  const int e = y;
  const int Q4 = 147456;   // 768*768/4
  const int W14 = 786432;  // 4096*768/4
  // phase 1: q/k/v/o weights (768x768 slice of 1024x1024), const divisors
  {
    const float* srcs[4] = { qw + (size_t)e * ND * ND, kw + (size_t)e * ND * ND,
                             vw + (size_t)e * ND * ND, ow + (size_t)e * ND * ND };
    ush* dsts[4] = { dq + (size_t)e * NW * NW, dk + (size_t)e * NW * NW,
                     dv + (size_t)e * NW * NW, dwo + (size_t)e * NW * NW };
    for (int u = u0; u < 4 * Q4; u += step) {
      int which = u / Q4, rel = u - which * Q4;     // const divisor
      int r = rel / 192, c = rel - r * 192;         // const divisor
      float4 v = *(const float4*)(srcs[which] + (size_t)r * ND + c * 4);
      u16x4 o; o.x = f2b(v.x); o.y = f2b(v.y); o.z = f2b(v.z); o.w = f2b(v.w);
      *(u16x4*)(dsts[which] + (size_t)rel * 4) = o;
    }
  }
  // phase 2: w1 (4096 rows x 768-col slice of 1024), const divisors
  {
    const float* s1 = w1 + (size_t)e * NF * ND;
    ush* t1 = d1 + (size_t)e * NF * NW;
    for (int u = u0; u < W14; u += step) {
      int r = u / 192, c = u - r * 192;
      float4 v = *(const float4*)(s1 + (size_t)r * ND + c * 4);
      u16x4 o; o.x = f2b(v.x); o.y = f2b(v.y); o.z = f2b(v.z); o.w = f2b(v.w);
      *(u16x4*)(t1 + (size_t)u * 4) = o;
    }
  }
  // phase 3: w2 (768 full rows of 1024x4096) -> fully contiguous linear copy
  {
    const float* s2 = w2 + (size_t)e * ND * NF;
    ush* t2 = d2 + (size_t)e * NW * NF;
    for (int u = u0; u < W14; u += step) {
      float4 v = *(const float4*)(s2 + (size_t)u * 4);
      u16x4 o; o.x = f2b(v.x); o.y = f2b(v.y); o.z = f2b(v.z); o.w = f2b(v.w);
      *(u16x4*)(t2 + (size_t)u * 4) = o;
    }
  }
}

#define BM 128
#define BN 128

// fast tanh-form gelu (~12 VALU vs ~30 for erff); |err| vs exact <~1e-3
__device__ __forceinline__ float gelu_fast(float v) {
  float u = v * fmaf(0.0356774081f, v * v, 0.7978845608f);
  float p = __expf(2.0f * fabsf(u));               // e^{2|u|} (inf-safe)
  float th = fmaf(-2.0f, __builtin_amdgcn_rcpf(p + 1.0f), 1.0f);
  th = copysignf(th, u);
  return 0.5f * v * (1.0f + th);
}

// staging-geometry (validated R9/R10): vrow u, pair offset PAIR
__device__ __forceinline__ void stage_geom2(int tid, int u, int PAIR, int& row, int& kb) {
  row = u + PAIR * (((tid >> 2) ^ (u >> 2)) & 1);
  kb = ((tid ^ u) & 3) << 4;
}

// ---------------- batched QKV GEMM (narrow 128x128, 3-slot BK=32 pipeline) ----------------
// 1-D grid nwg = 8*576; e = bid&7 (XCD-pinned), wi = bid>>3: bn=wi%6, bm=(wi/6)%32, w=wi/192
// V^T output transposed through LDS (reused pipeline slots) for coalesced writes.
__global__ __launch_bounds__(256, 3)
void qkv_gemm(const ush* __restrict__ A,
              const ush* __restrict__ wqb, const ush* __restrict__ wkb,
              const ush* __restrict__ wvb,
              const float* __restrict__ qbias, const float* __restrict__ kbias,
              const float* __restrict__ vbias,
              ush* __restrict__ qg, ush* __restrict__ kg, ush* __restrict__ vtg,
              const int* __restrict__ cnt64s, const int* __restrict__ idx_all) {
  const int bid = blockIdx.x;
  const int e = bid & 7, wi = bid >> 3;
  const int bn = wi % 6, bm = (wi / 6) % 32, w = wi / 192;
  int sb = 0, cnt = 0;
  if (w == 0) {
    int sec = e * 4 + (bm >> 3);
    cnt = cnt64s[sec];
    if (((bm & 7) * 128) >= cnt) return;
    sb = prefix_sum(cnt64s, sec);
  }
  const ush* Bw = ((w == 0) ? wqb : (w == 1) ? wkb : wvb) + (size_t)e * NW * NW;
  const float* bias = ((w == 0) ? qbias : (w == 1) ? kbias : vbias) + (size_t)e * ND;

  __shared__ __align__(16) char LDS[3 * 16384];

  const int tid = threadIdx.x, lane = tid & 63, wave = tid >> 6;
  const int lr = lane & 15, lg = lane >> 4;
  const int wr = wave >> 1, wc = wave & 1;

  size_t srcOff[4];
#pragma unroll
  for (int c = 0; c < 4; ++c) {
    int u = (c & 1) * 32 + (tid >> 3), row, kb;
    stage_geom2(tid, u, 64, row, kb);
    int gRow;
    if (c < 2) {
      if (w == 0) {
        int lrow = (bm & 7) * 128 + row;
        gRow = idx_all[(e * 4 + (bm >> 3)) * 1024 + lrow] & 0x7fffffff;
      } else {
        gRow = bm * BM + row;
      }
    } else {
      gRow = bn * BN + row;
    }
    srcOff[c] = (size_t)gRow * (NW * 2) + kb;
  }

  int offA[4], offB[4];
#pragma unroll
  for (int i = 0; i < 4; ++i) {
    offA[i] = (i * 16 + lr) * 128 + (((wr << 6) | (lg << 4)) ^ ((lr & 7) << 4));
    offB[i] = (i * 16 + lr) * 128 + (((wc << 6) | (lg << 4)) ^ ((lr & 7) << 4)) + 8192;
  }

  auto stg = [&](int slot, int kt) {
    size_t kOff = (size_t)kt * 64;
    char* dst = LDS + slot * 16384;
#pragma unroll
    for (int c = 0; c < 4; ++c) {
      const char* src = (c < 2) ? (const char*)A + srcOff[c] + kOff
                                : (const char*)Bw + srcOff[c] + kOff;
      gload16(src, dst + c * 4096 + tid * 16);
    }
  };

  f32x4 acc[4][4] = {};
  const int nkt = NW / 32;   // 24
  stg(0, 0); stg(1, 1);
  asm volatile("s_waitcnt vmcnt(4)" ::: "memory");
  asm volatile("s_barrier" ::: "memory");
  int slot = 0;
  for (int kt = 0; kt < nkt; ++kt) {
    int s2 = slot + 2; if (s2 >= 3) s2 -= 3;
    bool more = (kt + 2 < nkt);
    if (more) stg(s2, kt + 2);
    const char* base = LDS + slot * 16384;
    short8 af[4], bfr[4];
#pragma unroll
    for (int i = 0; i < 4; ++i) {
      af[i] = *(const short8*)(base + offA[i]);
      bfr[i] = *(const short8*)(base + offB[i]);
    }
    __builtin_amdgcn_s_setprio(1);
#pragma unroll
    for (int i = 0; i < 4; ++i)
#pragma unroll
      for (int j = 0; j < 4; ++j)
        acc[i][j] = __builtin_amdgcn_mfma_f32_16x16x32_bf16(af[i], bfr[j], acc[i][j], 0, 0, 0);
    __builtin_amdgcn_s_setprio(0);
    if (more) asm volatile("s_waitcnt vmcnt(4)" ::: "memory");
    else      asm volatile("s_waitcnt vmcnt(0)" ::: "memory");
    asm volatile("s_barrier" ::: "memory");
    slot = (slot == 2) ? 0 : slot + 1;
  }

  if (w == 2) {
    // V^T: transpose through LDS (pipeline slots dead after final barrier).
    // Tile T[d][s]: d=0..127 rows of 256B, byte addr = d*256 + ((s*2) ^ ((d&15)<<4)).
#pragma unroll
    for (int i = 0; i < 4; ++i) {
      int sl = wr * 64 + i * 16 + lg * 4;          // section-local s
#pragma unroll
      for (int j = 0; j < 4; ++j) {
        int d = wc * 64 + j * 16 + lr;
        float bb = bias[bn * BN + d];
        u16x4 wv_;
#pragma unroll
        for (int r = 0; r < 4; ++r) wv_[r] = f2b(acc[i][j][r] + bb);
        *(u16x4*)(LDS + d * 256 + ((sl * 2) ^ ((d & 15) << 4))) = wv_;
      }
    }
    __syncthreads();
    // stream out: thread -> (d = tid>>1, s-half = (tid&1)*64); 8 x 16B coalesced stores
    int d = tid >> 1, sh = (tid & 1) * 64;
    int b_ = bm >> 3, s0b = (bm & 7) * 128;
    ush* gdst = vtg + (size_t)e * VSTRIDE +
                ((size_t)(b_ * NH + bn) * NHD + d) * NS + s0b + sh;
#pragma unroll
    for (int c = 0; c < 8; ++c) {
      short8 v = *(const short8*)(LDS + d * 256 + (((sh + c * 8) * 2) ^ ((d & 15) << 4)));
      *(short8*)(gdst + c * 8) = v;
    }
    return;
  }

#pragma unroll
  for (int i = 0; i < 4; ++i) {
    int lm16 = (bm & 7) * 128 + wr * 64 + i * 16;            // Q: section-local 16-row group
    int m0 = bm * BM + wr * 64 + i * 16 + lg * 4;            // dense row
#pragma unroll
    for (int j = 0; j < 4; ++j) {
      int n = bn * BN + wc * 64 + j * 16 + lr;
      float bb = bias[n];
      if (w == 0) {
        if (lm16 < cnt) {
          int grow = sb + lm16 + lg * 4;
#pragma unroll
          for (int r = 0; r < 4; ++r)
            qg[(size_t)(grow + r) * NW + n] = f2b(acc[i][j][r] + bb);
        }
      } else {
        ush* o = kg + (size_t)e * NTOK * NW;
#pragma unroll
        for (int r = 0; r < 4; ++r)
          o[(size_t)(m0 + r) * NW + n] = f2b(acc[i][j][r] + bb);
      }
    }
  }
}

// ---------------- batched flash attention (R13-proven): full KV sweep, direct AO write ----------------
// 1-D grid 8*384; e = bid&7; wi = bid>>3: qb = wi&15, bh = wi>>4 in [0,24)
__global__ __launch_bounds__(256, 3)
void attn2(const ush* __restrict__ Qg, const ush* __restrict__ Kg,
           const ush* __restrict__ VTg, ush* __restrict__ ao,
           const int* __restrict__ cnt64s) {
  const int bid = blockIdx.x;
  const int e = bid & 7, wi = bid >> 3;
  const int qb = wi & 15, bh = wi >> 4;
  const int b = bh / NH, h = bh % NH;
  const int sec = e * 4 + b;
  const int cnt = cnt64s[sec];
  if (qb * 64 >= cnt) return;
  const int sb = prefix_sum(cnt64s, sec);

  __shared__ __align__(16) ush Ks[64 * 128];
  __shared__ __align__(16) ush VTs[128 * 64];
  __shared__ __align__(16) ush Ps[4 * 16 * 64];

  const int tid = threadIdx.x, lane = tid & 63, wave = tid >> 6;
  const int lr = lane & 15, lg = lane >> 4;
  const float cexp = 1.4426950408889634f / sqrtf((float)NHD);

  const ush* Ke = Kg + (size_t)e * NTOK * NW;
  const ush* Ve = VTg + (size_t)e * VSTRIDE;

  int growq = sb + qb * 64 + wave * 16 + lr;
  short8 qf[4];
#pragma unroll
  for (int kk = 0; kk < 4; ++kk)
    qf[kk] = *(const short8*)(Qg + (size_t)growq * NW + h * NHD + kk * 32 + lg * 8);

  f32x4 accv[8] = {};
  float mr[4] = {-3.0e38f, -3.0e38f, -3.0e38f, -3.0e38f};
  float ls[4] = {};

  for (int kt = 0; kt < 16; ++kt) {   // 16 x 64 keys = all 1024
    __syncthreads();
#pragma unroll
    for (int p = 0; p < 4; ++p) {
      int o = p * 4096 + tid * 16;
      int row = o >> 8, cb = o & 255;
      gload16((const char*)Ke + ((size_t)(b * NS + kt * 64 + row) * NW + h * NHD) * 2 +
                  (cb ^ ((row & 7) << 4)),
              (char*)Ks + o);
    }
#pragma unroll
    for (int p = 0; p < 4; ++p) {
      int o = p * 4096 + tid * 16;
      int d = o >> 7, cb = o & 127;
      gload16((const char*)Ve + ((size_t)((b * NH + h) * NHD + d) * NS + kt * 64) * 2 +
                  (cb ^ ((d & 7) << 4)),
              (char*)VTs + o);
    }
    __syncthreads();

    f32x4 s[4] = {};
    __builtin_amdgcn_s_setprio(1);
#pragma unroll
    for (int kg2 = 0; kg2 < 4; ++kg2)
#pragma unroll
      for (int kk = 0; kk < 4; ++kk) {
        int row = kg2 * 16 + lr;
        short8 kf = *(const short8*)((const char*)Ks + row * 256 +
                                     ((kk * 64 + lg * 16) ^ ((row & 7) << 4)));
        s[kg2] = __builtin_amdgcn_mfma_f32_16x16x32_bf16(qf[kk], kf, s[kg2], 0, 0, 0);
      }
    __builtin_amdgcn_s_setprio(0);

    float mt[4];
#pragma unroll
    for (int r = 0; r < 4; ++r) {
      float m0 = fmaxf(fmaxf(s[0][r], s[1][r]), fmaxf(s[2][r], s[3][r]));
#pragma unroll
      for (int mm = 1; mm < 16; mm <<= 1) m0 = fmaxf(m0, __shfl_xor(m0, mm));
      mt[r] = m0;
    }
    bool need = (mt[0] > mr[0] + 8.f) || (mt[1] > mr[1] + 8.f) ||
                (mt[2] > mr[2] + 8.f) || (mt[3] > mr[3] + 8.f);
    if (__any(need)) {
#pragma unroll
      for (int r = 0; r < 4; ++r) {
        float mn = fmaxf(mr[r], mt[r]);
        float sc = exp2f((mr[r] - mn) * cexp);
        mr[r] = mn; ls[r] *= sc;
#pragma unroll
        for (int dg = 0; dg < 8; ++dg) accv[dg][r] *= sc;
      }
    }

    char* pw = (char*)Ps + wave * 2048;
#pragma unroll
    for (int kg2 = 0; kg2 < 4; ++kg2)
#pragma unroll
      for (int r = 0; r < 4; ++r) {
        float p = exp2f((s[kg2][r] - mr[r]) * cexp);
        ls[r] += p;
        int row = lg * 4 + r;
        *(ush*)(pw + row * 128 + (((kg2 * 16 + lr) * 2) ^ ((row & 7) << 4))) = f2b(p);
      }
    short8 pf[2];
#pragma unroll
    for (int kk2 = 0; kk2 < 2; ++kk2)
      pf[kk2] = *(const short8*)(pw + lr * 128 + ((kk2 * 64 + lg * 16) ^ ((lr & 7) << 4)));

    __builtin_amdgcn_s_setprio(1);
#pragma unroll
    for (int dg = 0; dg < 8; ++dg) {
      int d = dg * 16 + lr;
#pragma unroll
      for (int kk2 = 0; kk2 < 2; ++kk2) {
        short8 vf = *(const short8*)((const char*)VTs + d * 128 +
                                     ((kk2 * 64 + lg * 16) ^ ((d & 7) << 4)));
        accv[dg] = __builtin_amdgcn_mfma_f32_16x16x32_bf16(pf[kk2], vf, accv[dg], 0, 0, 0);
      }
    }
    __builtin_amdgcn_s_setprio(0);
  }

  // reduce l across row group, normalize, write AO directly
#pragma unroll
  for (int r = 0; r < 4; ++r)
#pragma unroll
    for (int mm = 1; mm < 16; mm <<= 1) ls[r] += __shfl_xor(ls[r], mm);

#pragma unroll
  for (int r = 0; r < 4; ++r) {
    int growr = sb + qb * 64 + wave * 16 + lg * 4 + r;
    float inv_ = 1.0f / ls[r];
#pragma unroll
    for (int dg = 0; dg < 8; ++dg)
      ao[(size_t)growr * NW + h * NHD + dg * 16 + lr] = f2b(accv[dg][r] * inv_);
  }
}

// ---------------- CSR GEMM wide: 128x256 tile, 4x8 acc, 3-slot BK=32 pipeline (FFN1) ----------------
__global__ __launch_bounds__(256, 2)
void csr_gemm_w(const ush* __restrict__ A, const ush* __restrict__ Ball,
                const float* __restrict__ biasAll, ush* __restrict__ out,
                int N, int Kld, int klen, int nbn,
                int strideBe, int biasStride,
                const int* __restrict__ cnt64s) {
  const int bid = blockIdx.x;
  const int e = bid & 7, wi = bid >> 3;
  const int bn = wi % nbn, bm = wi / nbn;
  const int Re = cnt64s[e * 4] + cnt64s[e * 4 + 1] + cnt64s[e * 4 + 2] + cnt64s[e * 4 + 3];
  if (bm * BM >= Re) return;
  const int ebase = prefix_sum(cnt64s, e * 4);
  const ush* Bw = Ball + (size_t)e * strideBe;
  const float* bias = biasAll + (size_t)e * biasStride;

  __shared__ __align__(16) char LDS[3 * 24576];

  const int tid = threadIdx.x, lane = tid & 63, wave = tid >> 6;
  const int lr = lane & 15, lg = lane >> 4;
  const int wr = wave >> 1, wc = wave & 1;

  size_t srcOff[6];
#pragma unroll
  for (int c = 0; c < 2; ++c) {
    int u = c * 32 + (tid >> 3), row, kb;
    stage_geom2(tid, u, 64, row, kb);
    srcOff[c] = (size_t)(ebase + bm * BM + row) * (Kld * 2) + kb;
  }
#pragma unroll
  for (int c = 0; c < 4; ++c) {
    int u = c * 32 + (tid >> 3), row, kb;
    stage_geom2(tid, u, 128, row, kb);
    srcOff[2 + c] = (size_t)(bn * 256 + row) * (Kld * 2) + kb;
  }

  int offA[4], offB[8];
#pragma unroll
  for (int i = 0; i < 4; ++i)
    offA[i] = (i * 16 + lr) * 128 + (((wr << 6) | (lg << 4)) ^ ((lr & 7) << 4));
#pragma unroll
  for (int j = 0; j < 8; ++j)
    offB[j] = (j * 16 + lr) * 128 + (((wc << 6) | (lg << 4)) ^ ((lr & 7) << 4)) + 8192;

  auto stg = [&](int slot, int kt) {
    size_t kOff = (size_t)kt * 64;
    char* dst = LDS + slot * 24576;
#pragma unroll
    for (int c = 0; c < 2; ++c)
      gload16((const char*)A + srcOff[c] + kOff, dst + c * 4096 + tid * 16);
#pragma unroll
    for (int c = 0; c < 4; ++c)
      gload16((const char*)Bw + srcOff[2 + c] + kOff, dst + 8192 + c * 4096 + tid * 16);
  };

  f32x4 acc[4][8] = {};
  const int nkt = klen / 32;
  stg(0, 0); stg(1, 1);
  asm volatile("s_waitcnt vmcnt(6)" ::: "memory");
  asm volatile("s_barrier" ::: "memory");
  int slot = 0;
  for (int kt = 0; kt < nkt; ++kt) {
    int s2 = slot + 2; if (s2 >= 3) s2 -= 3;
    bool more = (kt + 2 < nkt);
    if (more) stg(s2, kt + 2);
    const char* base = LDS + slot * 24576;
    short8 af[4], bfr[8];
#pragma unroll
    for (int i = 0; i < 4; ++i) af[i] = *(const short8*)(base + offA[i]);
#pragma unroll
    for (int j = 0; j < 8; ++j) bfr[j] = *(const short8*)(base + offB[j]);
    __builtin_amdgcn_s_setprio(1);
#pragma unroll
    for (int i = 0; i < 4; ++i)
#pragma unroll
      for (int j = 0; j < 8; ++j)
        acc[i][j] = __builtin_amdgcn_mfma_f32_16x16x32_bf16(af[i], bfr[j], acc[i][j], 0, 0, 0);
    __builtin_amdgcn_s_setprio(0);
    if (more) asm volatile("s_waitcnt vmcnt(6)" ::: "memory");
    else      asm volatile("s_waitcnt vmcnt(0)" ::: "memory");
    asm volatile("s_barrier" ::: "memory");
    slot = (slot == 2) ? 0 : slot + 1;
  }

#pragma unroll
  for (int i = 0; i < 4; ++i) {
    int lm16 = bm * BM + wr * 64 + i * 16;
    if (lm16 >= Re) continue;
#pragma unroll
    for (int j = 0; j < 8; ++j) {
      int n = bn * 256 + wc * 128 + j * 16 + lr;
      float bb = bias[n];
      int row0 = ebase + lm16 + lg * 4;
#pragma unroll
      for (int r = 0; r < 4; ++r)
        out[(size_t)(row0 + r) * N + n] = f2b(gelu_fast(acc[i][j][r] + bb));
    }
  }
}

// ---------------- CSR GEMM (128x128, 3-slot BK=32 pipeline; o-proj & FFN2) ----------------
__global__ __launch_bounds__(256, 3)
void csr_gemm(const ush* __restrict__ A, const ush* __restrict__ Ball,
              const float* __restrict__ biasAll, ush* __restrict__ out,
              int N, int Kld, int klen, int nbn, int nbm, int nsplit,
              int strideBe, int biasStride,
              const int* __restrict__ cnt64s) {
  const int bid = blockIdx.x;
  const int e = bid & 7, wi = bid >> 3;
  const int bn = wi % nbn, bm = (wi / nbn) % nbm, s = wi / (nbn * nbm);
  const int Re = cnt64s[e * 4] + cnt64s[e * 4 + 1] + cnt64s[e * 4 + 2] + cnt64s[e * 4 + 3];
  if (bm * BM >= Re) return;
  const int ebase = prefix_sum(cnt64s, e * 4);
  const ush* Bw = Ball + (size_t)e * strideBe;
  const float* bias = (s == 0) ? biasAll + (size_t)e * biasStride : nullptr;
  const int koff = s * klen;
  ush* outp = out + (size_t)s * RCAP * N;

  __shared__ __align__(16) char LDS[3 * 16384];

  const int tid = threadIdx.x, lane = tid & 63, wave = tid >> 6;
  const int lr = lane & 15, lg = lane >> 4;
  const int wr = wave >> 1, wc = wave & 1;

  size_t srcOff[4];
#pragma unroll
  for (int c = 0; c < 4; ++c) {
    int u = (c & 1) * 32 + (tid >> 3), row, kb;
    stage_geom2(tid, u, 64, row, kb);
    int gRow = (c < 2) ? (ebase + bm * BM + row) : (bn * BN + row);
    srcOff[c] = (size_t)gRow * (Kld * 2) + (size_t)koff * 2 + kb;
  }

  int offA[4], offB[4];
#pragma unroll
  for (int i = 0; i < 4; ++i) {
    offA[i] = (i * 16 + lr) * 128 + (((wr << 6) | (lg << 4)) ^ ((lr & 7) << 4));
    offB[i] = (i * 16 + lr) * 128 + (((wc << 6) | (lg << 4)) ^ ((lr & 7) << 4)) + 8192;
  }

  auto stg = [&](int slot, int kt) {
    size_t kOff = (size_t)kt * 64;
    char* dst = LDS + slot * 16384;
#pragma unroll
    for (int c = 0; c < 4; ++c) {
      const char* src = (c < 2) ? (const char*)A + srcOff[c] + kOff
                                : (const char*)Bw + srcOff[c] + kOff;
      gload16(src, dst + c * 4096 + tid * 16);
    }
  };

  f32x4 acc[4][4] = {};
  const int nkt = klen / 32;
  stg(0, 0); stg(1, 1);
  asm volatile("s_waitcnt vmcnt(4)" ::: "memory");
  asm volatile("s_barrier" ::: "memory");
  int slot = 0;
  for (int kt = 0; kt < nkt; ++kt) {
    int s2 = slot + 2; if (s2 >= 3) s2 -= 3;
    bool more = (kt + 2 < nkt);
    if (more) stg(s2, kt + 2);
    const char* base = LDS + slot * 16384;
    short8 af[4], bfr[4];
#pragma unroll
    for (int i = 0; i < 4; ++i) {
      af[i] = *(const short8*)(base + offA[i]);
      bfr[i] = *(const short8*)(base + offB[i]);
    }
    __builtin_amdgcn_s_setprio(1);
#pragma unroll
    for (int i = 0; i < 4; ++i)
#pragma unroll
      for (int j = 0; j < 4; ++j)
        acc[i][j] = __builtin_amdgcn_mfma_f32_16x16x32_bf16(af[i], bfr[j], acc[i][j], 0, 0, 0);
    __builtin_amdgcn_s_setprio(0);
    if (more) asm volatile("s_waitcnt vmcnt(4)" ::: "memory");
    else      asm volatile("s_waitcnt vmcnt(0)" ::: "memory");
    asm volatile("s_barrier" ::: "memory");
    slot = (slot == 2) ? 0 : slot + 1;
  }

#pragma unroll
  for (int i = 0; i < 4; ++i) {
    int lm16 = bm * BM + wr * 64 + i * 16;
    if (lm16 >= Re) continue;                  // cross-expert guard (Re % 64 == 0)
#pragma unroll
    for (int j = 0; j < 4; ++j) {
      int n = bn * BN + wc * 64 + j * 16 + lr;
      float bb = bias ? bias[n] : 0.0f;
      int row0 = ebase + lm16 + lg * 4;
#pragma unroll
      for (int r = 0; r < 4; ++r)
        outp[(size_t)(row0 + r) * N + n] = f2b(acc[i][j][r] + bb);
    }
  }
}

// ---------------- residual + RMSNorm over compacted rows (single o-proj partial) ----------------
__global__ __launch_bounds__(256, 4)
void rmsnorm_res(const float* __restrict__ x, const ush* __restrict__ ooP,
                 ush* __restrict__ x1b, const int* __restrict__ cnt64s,
                 const int* __restrict__ idx_all) {
  int r = blockIdx.x;
  int base = 0, sec = -1, loc = 0;
#pragma unroll 1
  for (int i = 0; i < 32; ++i) {
    int cc = cnt64s[i];
    if (sec < 0 && r < base + cc) { sec = i; loc = r - base; }
    base += cc;
  }
  if (sec < 0) return;
  int t = idx_all[sec * 1024 + loc] & 0x7fffffff;
  __shared__ float red[4];
  int c = threadIdx.x, lane = c & 63, wave = c >> 6;
  float v[3]; float ss = 0.0f;
#pragma unroll
  for (int i = 0; i < 3; ++i) {
    int col = c + i * 256;
    float a = x[(size_t)t * ND + col] + b2f(ooP[(size_t)r * NW + col]);
    v[i] = a; ss += a * a;
  }
#pragma unroll
  for (int m = 1; m < 64; m <<= 1) ss += __shfl_xor(ss, m);
  if (lane == 0) red[wave] = ss;
  __syncthreads();
  float tot = red[0] + red[1] + red[2] + red[3];
  float scale = rsqrtf(tot / (float)NW + EPS);
#pragma unroll
  for (int i = 0; i < 3; ++i) {
    int col = c + i * 256;
    x1b[(size_t)r * NW + col] = f2b(v[i] * scale);
  }
}

// ---------------- final: per token, gather both experts, rmsnorm, gate-sum (1 ffp partial) ----------------
__global__ __launch_bounds__(256, 4)
void final_token(const ush* __restrict__ x1b, const ush* __restrict__ ffp,
                 const float* __restrict__ gate, const int* __restrict__ inv,
                 const int* __restrict__ cnt64s, float* __restrict__ out) {
  int t = blockIdx.x, c = threadIdx.x, lane = c & 63, wave = c >> 6;
  __shared__ float red[4];
  float acc[3] = {0.0f, 0.0f, 0.0f};
#pragma unroll 1
  for (int k = 0; k < 2; ++k) {
    int v = inv[t * 2 + k];
    if (v >= 0) {
      int e = v >> 12, pos = v & 0xfff;
      int b = t >> 10;
      int grow = prefix_sum(cnt64s, e * 4 + b) + pos;
      float g = gate[(size_t)t * NE + e];
      float vv[3]; float ss = 0.0f;
#pragma unroll
      for (int i = 0; i < 3; ++i) {
        int col = c + i * 256;
        float a = b2f(x1b[(size_t)grow * NW + col]) + b2f(ffp[(size_t)grow * NW + col]);
        vv[i] = a; ss += a * a;
      }
#pragma unroll
      for (int m = 1; m < 64; m <<= 1) ss += __shfl_xor(ss, m);
      if (lane == 0) red[wave] = ss;
      __syncthreads();
      float tot = red[0] + red[1] + red[2] + red[3];
      float scale = rsqrtf(tot / (float)NW + EPS) * g;
#pragma unroll
      for (int i = 0; i < 3; ++i) acc[i] += vv[i] * scale;
      __syncthreads();
    }
  }
#pragma unroll
  for (int i = 0; i < 3; ++i) out[(size_t)t * ND + c + i * 256] = acc[i];
  out[(size_t)t * ND + 768 + c] = 0.0f;
}

// ---------------- host ----------------
extern "C" void kernel_launch(void* const* d_in, const int* in_sizes, int n_in,
                              void* d_out, int out_size, void* d_ws, size_t ws_size,
                              hipStream_t stream) {
  (void)in_sizes; (void)n_in; (void)ws_size; (void)out_size;
  const float* x  = (const float*)d_in[0];
  const float* wr = (const float*)d_in[1];
  const float* qw = (const float*)d_in[2];
  const float* qbias = (const float*)d_in[3];
  const float* kw = (const float*)d_in[4];
  const float* kbias = (const float*)d_in[5];
  const float* vw = (const float*)d_in[6];
  const float* vbias = (const float*)d_in[7];
  const float* ow = (const float*)d_in[8];
  const float* obias = (const float*)d_in[9];
  const float* w1 = (const float*)d_in[10];
  const float* b1 = (const float*)d_in[11];
  const float* w2 = (const float*)d_in[12];
  const float* b2 = (const float*)d_in[13];
  float* out = (float*)d_out;
  char* ws = (char*)d_ws;

  size_t off = 0;
  auto alloc = [&](size_t bytes) {
    void* p = ws + off;
    off += (bytes + 255) & ~(size_t)255;
    return p;
  };
  float* gate = (float*)alloc((size_t)NTOK * NE * 4);
  int* cnt64s = (int*)alloc(32 * 4);
  int* idx_all = (int*)alloc((size_t)NE * NTOK * 4);
  int* inv = (int*)alloc((size_t)NTOK * 2 * 4);
  ush* xs  = (ush*)alloc((size_t)NTOK * NW * 2);
  ush* wqb = (ush*)alloc((size_t)NE * NW * NW * 2);
  ush* wkb = (ush*)alloc((size_t)NE * NW * NW * 2);
  ush* wvb = (ush*)alloc((size_t)NE * NW * NW * 2);
  ush* wob = (ush*)alloc((size_t)NE * NW * NW * 2);
  ush* w1b = (ush*)alloc((size_t)NE * NF * NW * 2);
  ush* w2b = (ush*)alloc((size_t)NE * NW * NF * 2);
  ush* x1b = (ush*)alloc((size_t)RCAP * NW * 2);
  // arena1: attn {qg, aog} -> ffn {hb}
  char* arena1 = (char*)alloc((size_t)RCAP * NF * 2);          // 86.0 MB
  ush* qg  = (ush*)arena1;                                      // RCAP*768*2 = 16.1 MB
  ush* aog = (ush*)(arena1 + 16121856);                         // RCAP*768*2 (dead before hb written)
  ush* hb  = (ush*)arena1;                                      // ffn phase (after aog consumed)
  // arena2: attn {kg, vtg} -> post {ooP, ffp}
  char* arena2 = (char*)alloc(112852992);
  ush* kg  = (ush*)arena2;                                      // 8*4096*768*2 = 50.3 MB
  ush* vtg = (ush*)(arena2 + 50331648);                         // 50.3 MB
  ush* ooP = (ush*)(arena2 + 16121856);                         // 1 partial 16.1 MB
  ush* ffp = (ush*)(arena2 + 32243712);                         // 1 partial 16.1 MB

  router_kernel<<<dim3(NTOK / 4), 256, 0, stream>>>(x, wr, gate, inv);
  build_index<<<dim3(NE * NB), 1024, 0, stream>>>(gate, cnt64s, idx_all, inv);
  cast_all<<<dim3(384, 9), 256, 0, stream>>>(x, qw, kw, vw, ow, w1, w2,
                                             xs, wqb, wkb, wvb, wob, w1b, w2b);

  // QKV narrow: per-expert 576 blocks (bn 6 x bm 32 x w 3); V^T coalesced via LDS transpose
  qkv_gemm<<<dim3(8 * 576), 256, 0, stream>>>(
      xs, wqb, wkb, wvb, qbias, kbias, vbias, qg, kg, vtg, cnt64s, idx_all);

  // attention (R13 structure): full KV sweep, direct AO write; per-expert 384 blocks
  attn2<<<dim3(8 * 384), 256, 0, stream>>>(qg, kg, vtg, aog, cnt64s);

  // o-proj: single K chunk; per-expert 192 blocks
  csr_gemm<<<dim3(8 * 192), 256, 0, stream>>>(
      aog, wob, obias, ooP, NW, NW, NW, 6, 32, 1, NW * NW, ND, cnt64s);

  rmsnorm_res<<<dim3(RCAP), 256, 0, stream>>>(x, ooP, x1b, cnt64s, idx_all);

  // FFN1 wide (gelu_fast): per-expert 512 blocks (bn 16 x bm 32)
  csr_gemm_w<<<dim3(8 * 512), 256, 0, stream>>>(
      x1b, w1b, b1, hb, NF, NW, NW, 16, NF * NW, NF, cnt64s);

  // FFN2: single K chunk (128-step pipeline); per-expert 192 blocks
  csr_gemm<<<dim3(8 * 192), 256, 0, stream>>>(
      hb, w2b, b2, ffp, NW, NF, NF, 6, 32, 1, NW * NF, ND, cnt64s);

  final_token<<<dim3(NTOK), 256, 0, stream>>>(x1b, ffp, gate, inv, cnt64s, out);
}